// Round 13
// baseline (534.150 us; speedup 1.0000x reference)
//
#include <hip/hip_runtime.h>
#include <hip/hip_bf16.h>
#include <cstddef>
#include <cstdint>

#define NM 50000
#define NA 50000
#define ND 500
#define FEAT 128
#define KDIM 768
#define BATCH 1024
#define NEDGE 1600000
#define MD 128            // ELL row capacity (deg ~ Poisson(32); P(>128) ~ 1e-38)

#define NBIN 196          // ceil(50000/256) node bins of 256 nodes
#define CAP 10240         // records per bin (expected 8163, 23 sigma headroom)
#define F1B 400           // fill_bin blocks
#define F1E (NEDGE / F1B) // 4000 edges per block (exact)

#define PB64 782          // ceil(50000/64) blocks per big projection (4 waves x 16 rows)

typedef __bf16 bf16_t;
typedef bf16_t bf16x8 __attribute__((ext_vector_type(8)));
typedef bf16_t bf16x4 __attribute__((ext_vector_type(4)));
typedef float f32x4 __attribute__((ext_vector_type(4)));
typedef float f32x2 __attribute__((ext_vector_type(2)));
typedef unsigned short u16;
typedef unsigned char u8;

__device__ __forceinline__ float sigf(float x) { return 1.0f / (1.0f + __expf(-x)); }

// ---- fp8 e4m3 (OCP) helpers: HW v_cvt pack/unpack ----
__device__ __forceinline__ float4 dec4fp8(uint32_t w) {
  f32x2 lo = __builtin_amdgcn_cvt_pk_f32_fp8(w, false);
  f32x2 hi = __builtin_amdgcn_cvt_pk_f32_fp8(w, true);
  return make_float4(lo[0], lo[1], hi[0], hi[1]);
}
__device__ __forceinline__ u8 enc1fp8(float a) {
  return (u8)(__builtin_amdgcn_cvt_pk_fp8_f32(a, a, 0, false) & 0xff);
}

// ---------------- fill pass 1: edges -> bin-bucketed packed records -----------
__global__ __launch_bounds__(256) void fill_bin(
    const int* __restrict__ src, const int* __restrict__ dst,
    int* __restrict__ bcur, uint32_t* __restrict__ rec /* [2*NBIN][CAP] */)
{
  __shared__ uint32_t edg[F1E];      // 16 KB
  __shared__ int hist[2 * NBIN];
  __shared__ int base[2 * NBIN];
  const int tid = threadIdx.x;
  for (int i = tid; i < 2 * NBIN; i += 256) hist[i] = 0;
  __syncthreads();
  const int e0 = blockIdx.x * F1E;
  for (int i = tid; i < F1E; i += 256) {
    int s = __builtin_nontemporal_load(&src[e0 + i]);
    int d = __builtin_nontemporal_load(&dst[e0 + i]);
    edg[i] = ((uint32_t)s << 16) | (uint32_t)d;
    atomicAdd(&hist[s >> 8], 1);
    atomicAdd(&hist[NBIN + (d >> 8)], 1);
  }
  __syncthreads();
  for (int i = tid; i < 2 * NBIN; i += 256) {
    int c = hist[i];
    base[i] = c ? atomicAdd(&bcur[i], c) : 0;
    hist[i] = 0;  // reuse as emit cursor
  }
  __syncthreads();
  for (int i = tid; i < F1E; i += 256) {
    uint32_t e = edg[i];
    int s = (int)(e >> 16), d = (int)(e & 0xffffu);
    int bm = s >> 8, ba = NBIN + (d >> 8);
    int rm = base[bm] + atomicAdd(&hist[bm], 1);
    int ra = base[ba] + atomicAdd(&hist[ba], 1);
    if (rm < CAP) rec[(size_t)bm * CAP + rm] = e;
    if (ra < CAP) rec[(size_t)ba * CAP + ra] = ((uint32_t)d << 16) | (uint32_t)s;
  }
}

// ---------------- fill pass 2: records -> ELL rows + exact degrees ------------
__global__ __launch_bounds__(256) void fill_ell2(
    const uint32_t* __restrict__ rec, const int* __restrict__ bcur,
    u16* __restrict__ adjm, u16* __restrict__ adja,
    int* __restrict__ cnt_m, int* __restrict__ cnt_a)
{
  __shared__ int cnt256[256];
  const int g = blockIdx.x;                 // 0..2*NBIN-1
  const int side = g >= NBIN;
  const int bin = side ? g - NBIN : g;
  u16* adj = side ? adja : adjm;
  int* cnt = side ? cnt_a : cnt_m;
  cnt256[threadIdx.x] = 0;
  __syncthreads();
  int n = bcur[g]; if (n > CAP) n = CAP;
  const uint32_t* rb = rec + (size_t)g * CAP;
  for (int i = threadIdx.x; i < n; i += 256) {
    uint32_t r = rb[i];
    int node = (int)(r >> 16);
    int rk = atomicAdd(&cnt256[node & 255], 1);
    if (rk < MD) adj[(size_t)node * MD + rk] = (u16)(r & 0xffffu);
  }
  __syncthreads();
  int node = bin * 256 + threadIdx.x;
  if (node < NM) cnt[node] = cnt256[threadIdx.x];
}

// ---------------- util: 4x weight transpose->bf16 + deg->dinv ----------------
__global__ __launch_bounds__(256) void util_kernel(
    const float* __restrict__ W0, const float* __restrict__ W1,
    const float* __restrict__ W2, const float* __restrict__ W3,
    bf16_t* __restrict__ T0, bf16_t* __restrict__ T1,
    bf16_t* __restrict__ T2, bf16_t* __restrict__ T3,
    const int* __restrict__ cnt_m, const int* __restrict__ cnt_a,
    float* __restrict__ dm, float* __restrict__ da)
{
  const int b = blockIdx.x;
  if (b < 512) {
    const float* W = (b < 128) ? W0 : (b < 256) ? W1 : (b < 384) ? W2 : W3;
    bf16_t* T      = (b < 128) ? T0 : (b < 256) ? T1 : (b < 384) ? T2 : T3;
    int c = b & 127;
    for (int k = threadIdx.x; k < KDIM; k += 256)
      T[(size_t)c * KDIM + k] = (bf16_t)W[(size_t)k * FEAT + c];
  } else {
    int i = (b - 512) * 256 + threadIdx.x;
    if (i < NM) { int c = cnt_m[i]; dm[i] = c > 0 ? rsqrtf((float)c) : 0.f; }
    if (i < NA) { int c = cnt_a[i]; da[i] = c > 0 ? rsqrtf((float)c) : 0.f; }
  }
}

// ---------------- wave-independent projection: 16 rows x 128 cols per wave ----
// C = sigmoid(A[M,768] @ W + b). OM: 0 = fp32 out, 2 = fp8 out (row-scaled).
// MFMA A/B fragments loaded DIRECTLY from global (lane l: row/col = l&15,
// k-offset = (l>>4)*8 — matches the verified 16x16x32 operand layout).
// No LDS, no barriers: waves free-run, loads pipeline across K iterations.
// B (Wt, 196KB) is L2-resident across the grid.
template<int OM>
__device__ __forceinline__ void proj_wave(
    const float* __restrict__ A, const bf16_t* __restrict__ Wt,
    const float* __restrict__ bias, void* __restrict__ Cout, int M, int rowBase,
    const float* __restrict__ rowscale, bf16_t* __restrict__ C2)
{
  const int lane = threadIdx.x & 63;
  const int r = lane & 15;
  const int kg = (lane >> 4) * 8;

  int rowL = rowBase + r; if (rowL > M - 1) rowL = M - 1;
  const float*  ap = A  + (size_t)rowL * KDIM + kg;
  const bf16_t* bp = Wt + (size_t)r * KDIM + kg;

  f32x4 acc[8];
  #pragma unroll
  for (int n = 0; n < 8; ++n) acc[n] = (f32x4){0.f, 0.f, 0.f, 0.f};

  float4 pa0 = *(const float4*)ap;
  float4 pa1 = *(const float4*)(ap + 4);

  for (int kt = 0; kt < KDIM / 32; ++kt) {
    const int k0 = kt * 32;
    bf16x8 a;
    a[0] = (bf16_t)pa0.x; a[1] = (bf16_t)pa0.y; a[2] = (bf16_t)pa0.z; a[3] = (bf16_t)pa0.w;
    a[4] = (bf16_t)pa1.x; a[5] = (bf16_t)pa1.y; a[6] = (bf16_t)pa1.z; a[7] = (bf16_t)pa1.w;
    if (kt + 1 < KDIM / 32) {       // A prefetch: overlaps B-load wait + MFMAs
      pa0 = *(const float4*)(ap + k0 + 32);
      pa1 = *(const float4*)(ap + k0 + 36);
    }
    bf16x8 b[8];
    #pragma unroll
    for (int n = 0; n < 8; ++n)
      b[n] = *(const bf16x8*)(bp + (size_t)n * 16 * KDIM + k0);
    #pragma unroll
    for (int n = 0; n < 8; ++n)
      acc[n] = __builtin_amdgcn_mfma_f32_16x16x32_bf16(a, b[n], acc[n], 0, 0, 0);
  }

  // C frag layout: col=lane&15, row=(lane>>4)*4+reg
  const int r0 = (lane >> 4) * 4;
  #pragma unroll
  for (int n = 0; n < 8; ++n) {
    int col = n * 16 + r;
    float bb = bias[col];
    #pragma unroll
    for (int rr = 0; rr < 4; ++rr) {
      int row = rowBase + r0 + rr;
      if (row < M) {
        float v = sigf(acc[n][rr] + bb);
        float sc = rowscale ? rowscale[row] : 1.0f;
        if constexpr (OM == 2)
          ((u8*)Cout)[(size_t)row * FEAT + col] = enc1fp8(v * sc);
        else
          ((float*)Cout)[(size_t)row * FEAT + col] = v * sc;
        if (C2) C2[(size_t)row * FEAT + col] = (bf16_t)(0.25f * v);
      }
    }
  }
}

// ---------------- ALL projections, one dispatch (1596 blocks, 4 waves each) ---
// [0,782): mashup->M0y8(fp8,dm); [782,1564): api->y0a8(fp8,da)+outA;
// [1564,1580): x->vmi; [1580,1588): domain->vkey; [1588,1596): domain->vval.
__global__ __launch_bounds__(256) void proj_all(
    const float* __restrict__ mashup, const float* __restrict__ api,
    const float* __restrict__ x, const float* __restrict__ domain,
    const bf16_t* __restrict__ wt0, const bf16_t* __restrict__ wt1,
    const bf16_t* __restrict__ wt2, const bf16_t* __restrict__ wt3,
    const float* __restrict__ bsde, const float* __restrict__ bkey,
    const float* __restrict__ bval, const float* __restrict__ bsie,
    u8* __restrict__ M0y8, u8* __restrict__ y0a8,
    float* __restrict__ vmi, float* __restrict__ vkey, float* __restrict__ vval,
    const float* __restrict__ dm, const float* __restrict__ da,
    bf16_t* __restrict__ outA)
{
  const int b = blockIdx.x;
  const int w = threadIdx.x >> 6;
  if (b < PB64)
    proj_wave<2>(mashup, wt0, bsde, M0y8, NM, b * 64 + w * 16, dm, nullptr);
  else if (b < 2 * PB64)
    proj_wave<2>(api, wt3, bsie, y0a8, NA, (b - PB64) * 64 + w * 16, da, outA);
  else if (b < 2 * PB64 + 16)
    proj_wave<0>(x, wt0, bsde, vmi, BATCH, (b - 2 * PB64) * 64 + w * 16, nullptr, nullptr);
  else if (b < 2 * PB64 + 24)
    proj_wave<0>(domain, wt1, bkey, vkey, ND, (b - 2 * PB64 - 16) * 64 + w * 16, nullptr, nullptr);
  else
    proj_wave<0>(domain, wt2, bval, vval, ND, (b - 2 * PB64 - 24) * 64 + w * 16, nullptr, nullptr);
}

// ---------------- attention (phase-B split across both thread halves) ---------
__global__ __launch_bounds__(256) void attn_kernel(
    const float* __restrict__ vmi, const float* __restrict__ vkey,
    const float* __restrict__ vval, bf16_t* __restrict__ zm)
{
  const int i = blockIdx.x;
  const int tid = threadIdx.x;
  __shared__ float vs[FEAT];
  __shared__ float al[ND];
  __shared__ float red[4];
  __shared__ float ps[256];
  __shared__ float totS;
  if (tid < FEAT) vs[tid] = vmi[(size_t)i * FEAT + tid];
  __syncthreads();
  float part = 0.f;
  for (int j = tid; j < ND; j += 256) {
    const float* kr = vkey + (size_t)j * FEAT;
    float dot = 0.f;
    #pragma unroll 8
    for (int k = 0; k < FEAT; k += 4) {
      float4 kv = *(const float4*)(kr + k);
      dot += vs[k] * kv.x + vs[k + 1] * kv.y + vs[k + 2] * kv.z + vs[k + 3] * kv.w;
    }
    al[j] = dot;
    part += dot;
  }
  #pragma unroll
  for (int o = 32; o > 0; o >>= 1) part += __shfl_down(part, o, 64);
  if ((tid & 63) == 0) red[tid >> 6] = part;
  __syncthreads();
  if (tid == 0) totS = red[0] + red[1] + red[2] + red[3];
  // phase B: thread = (half h, feature f); each half sums 250 of the 500 rows
  const int f = tid & 127, h = tid >> 7;
  float s = 0.f;
  const float* vv = vval + (size_t)h * 250 * FEAT + f;
  #pragma unroll 5
  for (int j = 0; j < 250; ++j) s += al[h * 250 + j] * vv[(size_t)j * FEAT];
  ps[tid] = s;
  __syncthreads();
  if (tid < FEAT) {
    float z = 0.5f * ((ps[tid] + ps[128 + tid]) / totS + vs[tid]);
    zm[(size_t)i * FEAT + tid] = (bf16_t)z;
  }
}

// ---------------- fp8 row-gather: half-wave per alternate neighbor ------------
__device__ __forceinline__ float4 gatherF8(const uint32_t* __restrict__ base32,
                                           const u16* __restrict__ row,
                                           int n, int half)
{
  float4 acc = make_float4(0.f, 0.f, 0.f, 0.f);
  int j = half;
  while (j + 14 < n) {
    int u[8];
    #pragma unroll
    for (int q = 0; q < 8; ++q) u[q] = row[j + 2 * q];
    uint32_t w[8];
    #pragma unroll
    for (int q = 0; q < 8; ++q) w[q] = base32[(size_t)u[q] * 32];
    #pragma unroll
    for (int q = 0; q < 8; ++q) {
      float4 v = dec4fp8(w[q]);
      acc.x += v.x; acc.y += v.y; acc.z += v.z; acc.w += v.w;
    }
    j += 16;
  }
  while (j < n) {
    float4 v = dec4fp8(base32[(size_t)row[j] * 32]);
    acc.x += v.x; acc.y += v.y; acc.z += v.z; acc.w += v.w;
    j += 2;
  }
  return acc;
}

#define REDUCE_HALVES(acc)                    \
  acc.x += __shfl_xor(acc.x, 32);             \
  acc.y += __shfl_xor(acc.y, 32);             \
  acc.z += __shfl_xor(acc.z, 32);             \
  acc.w += __shfl_xor(acc.w, 32);

// ---- pass1 (api side): y01a = y0a + da^2 * sum_{m in N(a)} M0y[m] ------------
__global__ __launch_bounds__(256) void prop_p1(
    const uint32_t* __restrict__ M0y8, const uint32_t* __restrict__ y0a8,
    uint32_t* __restrict__ y01a8,
    const u16* __restrict__ adja, const int* __restrict__ cnt_a,
    const float* __restrict__ da)
{
  const int a = blockIdx.x * 4 + (threadIdx.x >> 6);
  const int lane = threadIdx.x & 63;
  const int half = lane >> 5, sl = lane & 31;
  int n = cnt_a[a]; if (n > MD) n = MD;
  float4 acc = gatherF8(M0y8 + sl, adja + (size_t)a * MD, n, half);
  REDUCE_HALVES(acc)
  if (half == 0) {
    const float d = da[a];
    const float s2 = d * d;
    float4 b = dec4fp8(y0a8[(size_t)a * 32 + sl]);
    uint32_t o = __builtin_amdgcn_cvt_pk_fp8_f32(b.x + s2 * acc.x, b.y + s2 * acc.y, 0, false);
    o = __builtin_amdgcn_cvt_pk_fp8_f32(b.z + s2 * acc.z, b.w + s2 * acc.w, o, true);
    y01a8[(size_t)a * 32 + sl] = o;
  }
}

// ---- pass2 (mashup side): Sy = M0y + dm^2 * sum_{a in N(m)} y01a[a] ----------
__global__ __launch_bounds__(256) void prop_p2(
    const uint32_t* __restrict__ y01a8, const uint32_t* __restrict__ M0y8,
    uint32_t* __restrict__ Sy8,
    const u16* __restrict__ adjm, const int* __restrict__ cnt_m,
    const float* __restrict__ dm)
{
  const int m = blockIdx.x * 4 + (threadIdx.x >> 6);
  const int lane = threadIdx.x & 63;
  const int half = lane >> 5, sl = lane & 31;
  int n = cnt_m[m]; if (n > MD) n = MD;
  float4 acc = gatherF8(y01a8 + sl, adjm + (size_t)m * MD, n, half);
  REDUCE_HALVES(acc)
  if (half == 0) {
    const float d = dm[m];
    const float s2 = d * d;
    float4 b = dec4fp8(M0y8[(size_t)m * 32 + sl]);
    uint32_t o = __builtin_amdgcn_cvt_pk_fp8_f32(b.x + s2 * acc.x, b.y + s2 * acc.y, 0, false);
    o = __builtin_amdgcn_cvt_pk_fp8_f32(b.z + s2 * acc.z, b.w + s2 * acc.w, o, true);
    Sy8[(size_t)m * 32 + sl] = o;
  }
}

// ---- pass3 (api side): O = 0.25*A0 + 0.25*da * sum_{m in N(a)} Sy[m] ---------
__global__ __launch_bounds__(256) void prop_p3(
    const uint32_t* __restrict__ Sy8, const bf16_t* __restrict__ outA,
    bf16_t* __restrict__ Obf,
    const u16* __restrict__ adja, const int* __restrict__ cnt_a,
    const float* __restrict__ da)
{
  const int a = blockIdx.x * 4 + (threadIdx.x >> 6);
  const int lane = threadIdx.x & 63;
  const int half = lane >> 5, sl = lane & 31;
  int n = cnt_a[a]; if (n > MD) n = MD;
  float4 acc = gatherF8(Sy8 + sl, adja + (size_t)a * MD, n, half);
  REDUCE_HALVES(acc)
  if (half == 0) {
    const float q = 0.25f * da[a];
    bf16x4 pv = *(const bf16x4*)(outA + (size_t)a * FEAT + 4 * sl);
    bf16x4 o;
    o[0] = (bf16_t)((float)pv[0] + q * acc.x);
    o[1] = (bf16_t)((float)pv[1] + q * acc.y);
    o[2] = (bf16_t)((float)pv[2] + q * acc.z);
    o[3] = (bf16_t)((float)pv[3] + q * acc.w);
    *(bf16x4*)(Obf + (size_t)a * FEAT + 4 * sl) = o;
  }
}

// ---------------- pred = Z[1024,128] @ O[50000,128]^T, bf16 MFMA --------------
__global__ __launch_bounds__(256) void pred_mfma(
    const bf16_t* __restrict__ Z, const bf16_t* __restrict__ O,
    float* __restrict__ out)
{
  const int lane = threadIdx.x & 63;
  const int wid = threadIdx.x >> 6;
  const int nBase = blockIdx.x * 256 + wid * 64;
  const int cc = lane & 15;
  const int kOff = (lane >> 4) * 8;

  bf16x8 b[4][4];
  #pragma unroll
  for (int n = 0; n < 4; ++n) {
    int c = nBase + n * 16 + cc;
    if (c > NA - 1) c = NA - 1;
    #pragma unroll
    for (int kk = 0; kk < 4; ++kk)
      b[n][kk] = *(const bf16x8*)(O + (size_t)c * FEAT + kk * 32 + kOff);
  }

  const int r0 = (lane >> 4) * 4;
  #pragma unroll
  for (int it = 0; it < 4; ++it) {
    const int iBase = blockIdx.y * 256 + it * 64;
    f32x4 acc[4][4];
    #pragma unroll
    for (int m = 0; m < 4; ++m)
      #pragma unroll
      for (int n = 0; n < 4; ++n)
        acc[m][n] = (f32x4){0.f, 0.f, 0.f, 0.f};

    #pragma unroll
    for (int kk = 0; kk < 4; ++kk) {
      bf16x8 a[4];
      #pragma unroll
      for (int m = 0; m < 4; ++m)
        a[m] = *(const bf16x8*)(Z + (size_t)(iBase + cc + m * 16) * FEAT + kk * 32 + kOff);
      #pragma unroll
      for (int m = 0; m < 4; ++m)
        #pragma unroll
        for (int n = 0; n < 4; ++n)
          acc[m][n] = __builtin_amdgcn_mfma_f32_16x16x32_bf16(a[m], b[n][kk], acc[m][n], 0, 0, 0);
    }

    #pragma unroll
    for (int n = 0; n < 4; ++n) {
      int col = nBase + n * 16 + cc;
      if (col < NA) {
        #pragma unroll
        for (int m = 0; m < 4; ++m) {
          #pragma unroll
          for (int r = 0; r < 4; ++r) {
            int row = iBase + m * 16 + r0 + r;
            __builtin_nontemporal_store(acc[m][n][r], &out[(size_t)row * NA + col]);
          }
        }
      }
    }
  }
}

static inline char* alignup(char* p, size_t a) {
  return (char*)(((uintptr_t)p + a - 1) & ~(uintptr_t)(a - 1));
}

extern "C" void kernel_launch(void* const* d_in, const int* in_sizes, int n_in,
                              void* d_out, int out_size, void* d_ws, size_t ws_size,
                              hipStream_t stream) {
  const float* x      = (const float*)d_in[0];
  const float* mashup = (const float*)d_in[1];
  const float* domain = (const float*)d_in[2];
  const float* api    = (const float*)d_in[3];
  const float* Wsde   = (const float*)d_in[4];
  const float* bsde   = (const float*)d_in[5];
  const float* Wval   = (const float*)d_in[6];
  const float* bval   = (const float*)d_in[7];
  const float* Wkey   = (const float*)d_in[8];
  const float* bkey   = (const float*)d_in[9];
  const float* Wsie   = (const float*)d_in[10];
  const float* bsie   = (const float*)d_in[11];
  const int* esrc     = (const int*)d_in[12];
  const int* edst     = (const int*)d_in[13];
  float* out = (float*)d_out;

  // workspace layout (~90 MB)
  char* p = (char*)d_ws;
  u8*     M0y8  = (u8*)p; p += (size_t)NM * FEAT;                 // 6.4MB
  u8*     y0a8  = (u8*)p; p += (size_t)NA * FEAT;                 // 6.4MB
  u8*     y01a8 = (u8*)p; p += (size_t)NA * FEAT;                 // 6.4MB
  u8*     Sy8   = (u8*)p; p += (size_t)NM * FEAT;                 // 6.4MB
  bf16_t* outA  = (bf16_t*)p; p += (size_t)NA * FEAT * 2;         // 12.8MB
  bf16_t* Obf   = (bf16_t*)p; p += (size_t)NA * FEAT * 2;         // 12.8MB
  u16*    adjm  = (u16*)p;    p += (size_t)NM * MD * 2;           // 12.8MB
  u16*    adja  = (u16*)p;    p += (size_t)NA * MD * 2;           // 12.8MB
  float*  vmi   = (float*)p;  p += (size_t)BATCH * FEAT * 4;
  float*  vkey  = (float*)p;  p += (size_t)ND * FEAT * 4;
  float*  vval  = (float*)p;  p += (size_t)ND * FEAT * 4;
  bf16_t* zm    = (bf16_t*)p; p += (size_t)BATCH * FEAT * 2;
  int* cnt_m = (int*)p; p += (size_t)NM * 4;
  int* cnt_a = (int*)p; p += (size_t)NA * 4;
  float* dm  = (float*)p; p += (size_t)NM * 4;
  float* da  = (float*)p; p += (size_t)NA * 4;
  int* bcur  = (int*)p; p += 512 * 4;
  p = alignup(p, 16);
  bf16_t* wt0 = (bf16_t*)p; p += (size_t)FEAT * KDIM * 2;
  bf16_t* wt1 = (bf16_t*)p; p += (size_t)FEAT * KDIM * 2;
  bf16_t* wt2 = (bf16_t*)p; p += (size_t)FEAT * KDIM * 2;
  bf16_t* wt3 = (bf16_t*)p; p += (size_t)FEAT * KDIM * 2;
  // rec (2*NBIN*CAP*4B = 16.1MB) overlays M0y8+y0a8+y01a8 (19.2MB): dead
  // before proj_all/prop write those (fill_ell2 completes first, same stream).
  uint32_t* rec = (uint32_t*)M0y8;

  hipMemsetAsync(bcur, 0, 512 * sizeof(int), stream);

  // ---- graph build: two-level binning (157K global atomics vs 3.2M) ----
  fill_bin<<<F1B, 256, 0, stream>>>(esrc, edst, bcur, rec);
  fill_ell2<<<2 * NBIN, 256, 0, stream>>>(rec, bcur, adjm, adja, cnt_m, cnt_a);
  util_kernel<<<512 + (NM + 255) / 256, 256, 0, stream>>>(
      Wsde, Wkey, Wval, Wsie, wt0, wt1, wt2, wt3, cnt_m, cnt_a, dm, da);

  // ---- ALL projections in one dispatch (1596 blocks, wave-independent) ----
  proj_all<<<2 * PB64 + 32, 256, 0, stream>>>(
      mashup, api, x, domain, wt0, wt1, wt2, wt3,
      bsde, bkey, bval, bsie, M0y8, y0a8, vmi, vkey, vval, dm, da, outA);

  attn_kernel<<<BATCH, 256, 0, stream>>>(vmi, vkey, vval, zm);

  // ---- bipartite LightGCN (fp8 gathers): out_api = 0.25*(A0 + P^T(M0+M1+M2)) ----
  prop_p1<<<NA / 4, 256, 0, stream>>>((const uint32_t*)M0y8, (const uint32_t*)y0a8,
                                      (uint32_t*)y01a8, adja, cnt_a, da);
  prop_p2<<<NM / 4, 256, 0, stream>>>((const uint32_t*)y01a8, (const uint32_t*)M0y8,
                                      (uint32_t*)Sy8, adjm, cnt_m, dm);
  prop_p3<<<NA / 4, 256, 0, stream>>>((const uint32_t*)Sy8, outA, Obf,
                                      adja, cnt_a, da);

  pred_mfma<<<dim3((NA + 255) / 256, BATCH / 256), 256, 0, stream>>>(zm, Obf, out);
}

// Round 14
// 454.245 us; speedup vs baseline: 1.1759x; 1.1759x over previous
//
#include <hip/hip_runtime.h>
#include <hip/hip_bf16.h>
#include <cstddef>
#include <cstdint>

#define NM 50000
#define NA 50000
#define ND 500
#define FEAT 128
#define KDIM 768
#define BATCH 1024
#define NEDGE 1600000
#define MD 128            // ELL row capacity (deg ~ Poisson(32); P(>128) ~ 1e-38)

#define NBIN 196          // ceil(50000/256) node bins of 256 nodes
#define CAP 10240         // records per bin (expected 8163, 23 sigma headroom)
#define F1B 400           // fill_bin blocks
#define F1E (NEDGE / F1B) // 4000 edges per block (exact)

#define PB64 782          // ceil(50000/64) blocks per big projection (BM=64)
#define PKT  24           // K tiles (768/32)

typedef __bf16 bf16_t;
typedef bf16_t bf16x8 __attribute__((ext_vector_type(8)));
typedef bf16_t bf16x4 __attribute__((ext_vector_type(4)));
typedef float f32x4 __attribute__((ext_vector_type(4)));
typedef float f32x2 __attribute__((ext_vector_type(2)));
typedef unsigned short u16;
typedef unsigned char u8;

__device__ __forceinline__ float sigf(float x) { return 1.0f / (1.0f + __expf(-x)); }

// ---- fp8 e4m3 (OCP) helpers: HW v_cvt pack/unpack ----
__device__ __forceinline__ float4 dec4fp8(uint32_t w) {
  f32x2 lo = __builtin_amdgcn_cvt_pk_f32_fp8(w, false);
  f32x2 hi = __builtin_amdgcn_cvt_pk_f32_fp8(w, true);
  return make_float4(lo[0], lo[1], hi[0], hi[1]);
}
__device__ __forceinline__ u8 enc1fp8(float a) {
  return (u8)(__builtin_amdgcn_cvt_pk_fp8_f32(a, a, 0, false) & 0xff);
}

// ---- async global->LDS, 16B per lane (dest = wave-uniform base + lane*16) ----
__device__ __forceinline__ void gll16(const void* g, void* l) {
  __builtin_amdgcn_global_load_lds(
      (const __attribute__((address_space(1))) unsigned int*)g,
      (__attribute__((address_space(3))) unsigned int*)l, 16, 0, 0);
}

// ---------------- fill pass 1: edges -> bin-bucketed packed records -----------
__global__ __launch_bounds__(256) void fill_bin(
    const int* __restrict__ src, const int* __restrict__ dst,
    int* __restrict__ bcur, uint32_t* __restrict__ rec /* [2*NBIN][CAP] */)
{
  __shared__ uint32_t edg[F1E];      // 16 KB
  __shared__ int hist[2 * NBIN];
  __shared__ int base[2 * NBIN];
  const int tid = threadIdx.x;
  for (int i = tid; i < 2 * NBIN; i += 256) hist[i] = 0;
  __syncthreads();
  const int e0 = blockIdx.x * F1E;
  for (int i = tid; i < F1E; i += 256) {
    int s = __builtin_nontemporal_load(&src[e0 + i]);
    int d = __builtin_nontemporal_load(&dst[e0 + i]);
    edg[i] = ((uint32_t)s << 16) | (uint32_t)d;
    atomicAdd(&hist[s >> 8], 1);
    atomicAdd(&hist[NBIN + (d >> 8)], 1);
  }
  __syncthreads();
  for (int i = tid; i < 2 * NBIN; i += 256) {
    int c = hist[i];
    base[i] = c ? atomicAdd(&bcur[i], c) : 0;
    hist[i] = 0;  // reuse as emit cursor
  }
  __syncthreads();
  for (int i = tid; i < F1E; i += 256) {
    uint32_t e = edg[i];
    int s = (int)(e >> 16), d = (int)(e & 0xffffu);
    int bm = s >> 8, ba = NBIN + (d >> 8);
    int rm = base[bm] + atomicAdd(&hist[bm], 1);
    int ra = base[ba] + atomicAdd(&hist[ba], 1);
    if (rm < CAP) rec[(size_t)bm * CAP + rm] = e;
    if (ra < CAP) rec[(size_t)ba * CAP + ra] = ((uint32_t)d << 16) | (uint32_t)s;
  }
}

// ---------------- fill pass 2: records -> ELL rows + exact degrees ------------
__global__ __launch_bounds__(256) void fill_ell2(
    const uint32_t* __restrict__ rec, const int* __restrict__ bcur,
    u16* __restrict__ adjm, u16* __restrict__ adja,
    int* __restrict__ cnt_m, int* __restrict__ cnt_a)
{
  __shared__ int cnt256[256];
  const int g = blockIdx.x;                 // 0..2*NBIN-1
  const int side = g >= NBIN;
  const int bin = side ? g - NBIN : g;
  u16* adj = side ? adja : adjm;
  int* cnt = side ? cnt_a : cnt_m;
  cnt256[threadIdx.x] = 0;
  __syncthreads();
  int n = bcur[g]; if (n > CAP) n = CAP;
  const uint32_t* rb = rec + (size_t)g * CAP;
  for (int i = threadIdx.x; i < n; i += 256) {
    uint32_t r = rb[i];
    int node = (int)(r >> 16);
    int rk = atomicAdd(&cnt256[node & 255], 1);
    if (rk < MD) adj[(size_t)node * MD + rk] = (u16)(r & 0xffffu);
  }
  __syncthreads();
  int node = bin * 256 + threadIdx.x;
  if (node < NM) cnt[node] = cnt256[threadIdx.x];
}

// ---------------- util: 4x weight transpose->bf16 + deg->dinv ----------------
__global__ __launch_bounds__(256) void util_kernel(
    const float* __restrict__ W0, const float* __restrict__ W1,
    const float* __restrict__ W2, const float* __restrict__ W3,
    bf16_t* __restrict__ T0, bf16_t* __restrict__ T1,
    bf16_t* __restrict__ T2, bf16_t* __restrict__ T3,
    const int* __restrict__ cnt_m, const int* __restrict__ cnt_a,
    float* __restrict__ dm, float* __restrict__ da)
{
  const int b = blockIdx.x;
  if (b < 512) {
    const float* W = (b < 128) ? W0 : (b < 256) ? W1 : (b < 384) ? W2 : W3;
    bf16_t* T      = (b < 128) ? T0 : (b < 256) ? T1 : (b < 384) ? T2 : T3;
    int c = b & 127;
    for (int k = threadIdx.x; k < KDIM; k += 256)
      T[(size_t)c * KDIM + k] = (bf16_t)W[(size_t)k * FEAT + c];
  } else {
    int i = (b - 512) * 256 + threadIdx.x;
    if (i < NM) { int c = cnt_m[i]; dm[i] = c > 0 ? rsqrtf((float)c) : 0.f; }
    if (i < NA) { int c = cnt_a[i]; da[i] = c > 0 ? rsqrtf((float)c) : 0.f; }
  }
}

// ---------------- projection, BM=64, global_load_lds + dbuf + counted vmcnt ---
// C = sigmoid(A[M,768] @ W + b). OM: 0 = fp32 out, 2 = fp8 out (row-scaled).
// Fragment-major LDS (conflict-free b128 reads); each wave stages its quarter
// (A-frag wid as two 16B half-planes; B-frags 2wid,2wid+1). Double-buffered;
// per-wave s_waitcnt vmcnt(4) + raw s_barrier keeps next tile's loads in
// flight across the barrier (no vmcnt(0) drain in the loop).
template<int OM>
__device__ __forceinline__ void proj_body(
    const float* __restrict__ A, const bf16_t* __restrict__ Wt,
    const float* __restrict__ bias, void* __restrict__ Cout, int M, int rowBase,
    const float* __restrict__ rowscale, bf16_t* __restrict__ C2)
{
  __shared__ alignas(16) char smraw[2][16384];  // [buf][A 8KB | B 8KB]
  const int tid = threadIdx.x;
  const int lane = tid & 63;
  const int wid = tid >> 6;

  // staging sources (per-lane; 16B granules, lines fully covered per frag)
  int arow = rowBase + wid * 16 + (lane & 15); if (arow > M - 1) arow = M - 1;
  const float*  asrc  = A  + (size_t)arow * KDIM + ((lane >> 4) * 8);
  const bf16_t* bsrc0 = Wt + (size_t)((2 * wid) * 16 + (lane & 15)) * KDIM + ((lane >> 4) * 8);
  const bf16_t* bsrc1 = Wt + (size_t)((2 * wid + 1) * 16 + (lane & 15)) * KDIM + ((lane >> 4) * 8);

  f32x4 acc[2][4];
  #pragma unroll
  for (int m = 0; m < 2; ++m)
    #pragma unroll
    for (int n = 0; n < 4; ++n)
      acc[m][n] = (f32x4){0.f, 0.f, 0.f, 0.f};

  const int fA = (wid >> 1) * 2;        // this wave's A frags: fA, fA+1
  const int fB = (wid & 1) * 4;         // this wave's B frags: fB..fB+3

  int cur = 0;
  {  // prologue: stage tile 0
    char* base = smraw[0];
    gll16(asrc,      base + wid * 2048);
    gll16(asrc + 4,  base + wid * 2048 + 1024);
    gll16(bsrc0,     base + 8192 + (2 * wid) * 1024);
    gll16(bsrc1,     base + 8192 + (2 * wid + 1) * 1024);
  }

  for (int kt = 0; kt < PKT; ++kt) {
    if (kt + 1 < PKT) {
      const int k0 = (kt + 1) * 32;
      char* base = smraw[cur ^ 1];
      gll16(asrc + k0,      base + wid * 2048);
      gll16(asrc + k0 + 4,  base + wid * 2048 + 1024);
      gll16(bsrc0 + k0,     base + 8192 + (2 * wid) * 1024);
      gll16(bsrc1 + k0,     base + 8192 + (2 * wid + 1) * 1024);
      asm volatile("s_waitcnt vmcnt(4)" ::: "memory");
    } else {
      asm volatile("s_waitcnt vmcnt(0)" ::: "memory");
    }
    __builtin_amdgcn_s_barrier();
    asm volatile("" ::: "memory");

    const char* bb = smraw[cur];
    bf16x8 a[2], b[4];
    #pragma unroll
    for (int m = 0; m < 2; ++m) {
      f32x4 lo = *(const f32x4*)(bb + (fA + m) * 2048 + lane * 16);
      f32x4 hi = *(const f32x4*)(bb + (fA + m) * 2048 + 1024 + lane * 16);
      bf16x8 t;
      t[0] = (bf16_t)lo[0]; t[1] = (bf16_t)lo[1]; t[2] = (bf16_t)lo[2]; t[3] = (bf16_t)lo[3];
      t[4] = (bf16_t)hi[0]; t[5] = (bf16_t)hi[1]; t[6] = (bf16_t)hi[2]; t[7] = (bf16_t)hi[3];
      a[m] = t;
    }
    #pragma unroll
    for (int n = 0; n < 4; ++n)
      b[n] = *(const bf16x8*)(bb + 8192 + (fB + n) * 1024 + lane * 16);
    #pragma unroll
    for (int m = 0; m < 2; ++m)
      #pragma unroll
      for (int n = 0; n < 4; ++n)
        acc[m][n] = __builtin_amdgcn_mfma_f32_16x16x32_bf16(a[m], b[n], acc[m][n], 0, 0, 0);

    asm volatile("" ::: "memory");
    __builtin_amdgcn_s_barrier();
    cur ^= 1;
  }

  // C frag layout: col=lane&15, row=(lane>>4)*4+reg
  const int wRow = (wid >> 1) * 32, wCol = (wid & 1) * 64;
  const int r0 = (lane >> 4) * 4, cc = lane & 15;
  #pragma unroll
  for (int n = 0; n < 4; ++n) {
    int col = wCol + n * 16 + cc;
    float bb = bias[col];
    #pragma unroll
    for (int m = 0; m < 2; ++m) {
      #pragma unroll
      for (int r = 0; r < 4; ++r) {
        int row = rowBase + wRow + m * 16 + r0 + r;
        if (row < M) {
          float v = sigf(acc[m][n][r] + bb);
          float sc = rowscale ? rowscale[row] : 1.0f;
          if constexpr (OM == 2)
            ((u8*)Cout)[(size_t)row * FEAT + col] = enc1fp8(v * sc);
          else
            ((float*)Cout)[(size_t)row * FEAT + col] = v * sc;
          if (C2) C2[(size_t)row * FEAT + col] = (bf16_t)(0.25f * v);
        }
      }
    }
  }
}

// ---------------- ALL projections, one dispatch (1596 blocks, BM=64) ----------
// [0,782): mashup->M0y8(fp8,dm); [782,1564): api->y0a8(fp8,da)+outA;
// [1564,1580): x->vmi; [1580,1588): domain->vkey; [1588,1596): domain->vval.
__global__ __launch_bounds__(256) void proj_all(
    const float* __restrict__ mashup, const float* __restrict__ api,
    const float* __restrict__ x, const float* __restrict__ domain,
    const bf16_t* __restrict__ wt0, const bf16_t* __restrict__ wt1,
    const bf16_t* __restrict__ wt2, const bf16_t* __restrict__ wt3,
    const float* __restrict__ bsde, const float* __restrict__ bkey,
    const float* __restrict__ bval, const float* __restrict__ bsie,
    u8* __restrict__ M0y8, u8* __restrict__ y0a8,
    float* __restrict__ vmi, float* __restrict__ vkey, float* __restrict__ vval,
    const float* __restrict__ dm, const float* __restrict__ da,
    bf16_t* __restrict__ outA)
{
  const int b = blockIdx.x;
  if (b < PB64)
    proj_body<2>(mashup, wt0, bsde, M0y8, NM, b * 64, dm, nullptr);
  else if (b < 2 * PB64)
    proj_body<2>(api, wt3, bsie, y0a8, NA, (b - PB64) * 64, da, outA);
  else if (b < 2 * PB64 + 16)
    proj_body<0>(x, wt0, bsde, vmi, BATCH, (b - 2 * PB64) * 64, nullptr, nullptr);
  else if (b < 2 * PB64 + 24)
    proj_body<0>(domain, wt1, bkey, vkey, ND, (b - 2 * PB64 - 16) * 64, nullptr, nullptr);
  else
    proj_body<0>(domain, wt2, bval, vval, ND, (b - 2 * PB64 - 24) * 64, nullptr, nullptr);
}

// ---------------- attention (phase-B split across both thread halves) ---------
__global__ __launch_bounds__(256) void attn_kernel(
    const float* __restrict__ vmi, const float* __restrict__ vkey,
    const float* __restrict__ vval, bf16_t* __restrict__ zm)
{
  const int i = blockIdx.x;
  const int tid = threadIdx.x;
  __shared__ float vs[FEAT];
  __shared__ float al[ND];
  __shared__ float red[4];
  __shared__ float ps[256];
  __shared__ float totS;
  if (tid < FEAT) vs[tid] = vmi[(size_t)i * FEAT + tid];
  __syncthreads();
  float part = 0.f;
  for (int j = tid; j < ND; j += 256) {
    const float* kr = vkey + (size_t)j * FEAT;
    float dot = 0.f;
    #pragma unroll 8
    for (int k = 0; k < FEAT; k += 4) {
      float4 kv = *(const float4*)(kr + k);
      dot += vs[k] * kv.x + vs[k + 1] * kv.y + vs[k + 2] * kv.z + vs[k + 3] * kv.w;
    }
    al[j] = dot;
    part += dot;
  }
  #pragma unroll
  for (int o = 32; o > 0; o >>= 1) part += __shfl_down(part, o, 64);
  if ((tid & 63) == 0) red[tid >> 6] = part;
  __syncthreads();
  if (tid == 0) totS = red[0] + red[1] + red[2] + red[3];
  // phase B: thread = (half h, feature f); each half sums 250 of the 500 rows
  const int f = tid & 127, h = tid >> 7;
  float s = 0.f;
  const float* vv = vval + (size_t)h * 250 * FEAT + f;
  #pragma unroll 5
  for (int j = 0; j < 250; ++j) s += al[h * 250 + j] * vv[(size_t)j * FEAT];
  ps[tid] = s;
  __syncthreads();
  if (tid < FEAT) {
    float z = 0.5f * ((ps[tid] + ps[128 + tid]) / totS + vs[tid]);
    zm[(size_t)i * FEAT + tid] = (bf16_t)z;
  }
}

// ---------------- fp8 row-gather: half-wave per alternate neighbor ------------
__device__ __forceinline__ float4 gatherF8(const uint32_t* __restrict__ base32,
                                           const u16* __restrict__ row,
                                           int n, int half)
{
  float4 acc = make_float4(0.f, 0.f, 0.f, 0.f);
  int j = half;
  while (j + 14 < n) {
    int u[8];
    #pragma unroll
    for (int q = 0; q < 8; ++q) u[q] = row[j + 2 * q];
    uint32_t w[8];
    #pragma unroll
    for (int q = 0; q < 8; ++q) w[q] = base32[(size_t)u[q] * 32];
    #pragma unroll
    for (int q = 0; q < 8; ++q) {
      float4 v = dec4fp8(w[q]);
      acc.x += v.x; acc.y += v.y; acc.z += v.z; acc.w += v.w;
    }
    j += 16;
  }
  while (j < n) {
    float4 v = dec4fp8(base32[(size_t)row[j] * 32]);
    acc.x += v.x; acc.y += v.y; acc.z += v.z; acc.w += v.w;
    j += 2;
  }
  return acc;
}

#define REDUCE_HALVES(acc)                    \
  acc.x += __shfl_xor(acc.x, 32);             \
  acc.y += __shfl_xor(acc.y, 32);             \
  acc.z += __shfl_xor(acc.z, 32);             \
  acc.w += __shfl_xor(acc.w, 32);

// ---- pass1 (api side): y01a = y0a + da^2 * sum_{m in N(a)} M0y[m] ------------
__global__ __launch_bounds__(256) void prop_p1(
    const uint32_t* __restrict__ M0y8, const uint32_t* __restrict__ y0a8,
    uint32_t* __restrict__ y01a8,
    const u16* __restrict__ adja, const int* __restrict__ cnt_a,
    const float* __restrict__ da)
{
  const int a = blockIdx.x * 4 + (threadIdx.x >> 6);
  const int lane = threadIdx.x & 63;
  const int half = lane >> 5, sl = lane & 31;
  int n = cnt_a[a]; if (n > MD) n = MD;
  float4 acc = gatherF8(M0y8 + sl, adja + (size_t)a * MD, n, half);
  REDUCE_HALVES(acc)
  if (half == 0) {
    const float d = da[a];
    const float s2 = d * d;
    float4 b = dec4fp8(y0a8[(size_t)a * 32 + sl]);
    uint32_t o = __builtin_amdgcn_cvt_pk_fp8_f32(b.x + s2 * acc.x, b.y + s2 * acc.y, 0, false);
    o = __builtin_amdgcn_cvt_pk_fp8_f32(b.z + s2 * acc.z, b.w + s2 * acc.w, o, true);
    y01a8[(size_t)a * 32 + sl] = o;
  }
}

// ---- pass2 (mashup side): Sy = M0y + dm^2 * sum_{a in N(m)} y01a[a] ----------
__global__ __launch_bounds__(256) void prop_p2(
    const uint32_t* __restrict__ y01a8, const uint32_t* __restrict__ M0y8,
    uint32_t* __restrict__ Sy8,
    const u16* __restrict__ adjm, const int* __restrict__ cnt_m,
    const float* __restrict__ dm)
{
  const int m = blockIdx.x * 4 + (threadIdx.x >> 6);
  const int lane = threadIdx.x & 63;
  const int half = lane >> 5, sl = lane & 31;
  int n = cnt_m[m]; if (n > MD) n = MD;
  float4 acc = gatherF8(y01a8 + sl, adjm + (size_t)m * MD, n, half);
  REDUCE_HALVES(acc)
  if (half == 0) {
    const float d = dm[m];
    const float s2 = d * d;
    float4 b = dec4fp8(M0y8[(size_t)m * 32 + sl]);
    uint32_t o = __builtin_amdgcn_cvt_pk_fp8_f32(b.x + s2 * acc.x, b.y + s2 * acc.y, 0, false);
    o = __builtin_amdgcn_cvt_pk_fp8_f32(b.z + s2 * acc.z, b.w + s2 * acc.w, o, true);
    Sy8[(size_t)m * 32 + sl] = o;
  }
}

// ---- pass3 (api side): O = 0.25*A0 + 0.25*da * sum_{m in N(a)} Sy[m] ---------
__global__ __launch_bounds__(256) void prop_p3(
    const uint32_t* __restrict__ Sy8, const bf16_t* __restrict__ outA,
    bf16_t* __restrict__ Obf,
    const u16* __restrict__ adja, const int* __restrict__ cnt_a,
    const float* __restrict__ da)
{
  const int a = blockIdx.x * 4 + (threadIdx.x >> 6);
  const int lane = threadIdx.x & 63;
  const int half = lane >> 5, sl = lane & 31;
  int n = cnt_a[a]; if (n > MD) n = MD;
  float4 acc = gatherF8(Sy8 + sl, adja + (size_t)a * MD, n, half);
  REDUCE_HALVES(acc)
  if (half == 0) {
    const float q = 0.25f * da[a];
    bf16x4 pv = *(const bf16x4*)(outA + (size_t)a * FEAT + 4 * sl);
    bf16x4 o;
    o[0] = (bf16_t)((float)pv[0] + q * acc.x);
    o[1] = (bf16_t)((float)pv[1] + q * acc.y);
    o[2] = (bf16_t)((float)pv[2] + q * acc.z);
    o[3] = (bf16_t)((float)pv[3] + q * acc.w);
    *(bf16x4*)(Obf + (size_t)a * FEAT + 4 * sl) = o;
  }
}

// ---------------- pred = Z[1024,128] @ O[50000,128]^T, bf16 MFMA --------------
__global__ __launch_bounds__(256) void pred_mfma(
    const bf16_t* __restrict__ Z, const bf16_t* __restrict__ O,
    float* __restrict__ out)
{
  const int lane = threadIdx.x & 63;
  const int wid = threadIdx.x >> 6;
  const int nBase = blockIdx.x * 256 + wid * 64;
  const int cc = lane & 15;
  const int kOff = (lane >> 4) * 8;

  bf16x8 b[4][4];
  #pragma unroll
  for (int n = 0; n < 4; ++n) {
    int c = nBase + n * 16 + cc;
    if (c > NA - 1) c = NA - 1;
    #pragma unroll
    for (int kk = 0; kk < 4; ++kk)
      b[n][kk] = *(const bf16x8*)(O + (size_t)c * FEAT + kk * 32 + kOff);
  }

  const int r0 = (lane >> 4) * 4;
  #pragma unroll
  for (int it = 0; it < 4; ++it) {
    const int iBase = blockIdx.y * 256 + it * 64;
    f32x4 acc[4][4];
    #pragma unroll
    for (int m = 0; m < 4; ++m)
      #pragma unroll
      for (int n = 0; n < 4; ++n)
        acc[m][n] = (f32x4){0.f, 0.f, 0.f, 0.f};

    #pragma unroll
    for (int kk = 0; kk < 4; ++kk) {
      bf16x8 a[4];
      #pragma unroll
      for (int m = 0; m < 4; ++m)
        a[m] = *(const bf16x8*)(Z + (size_t)(iBase + cc + m * 16) * FEAT + kk * 32 + kOff);
      #pragma unroll
      for (int m = 0; m < 4; ++m)
        #pragma unroll
        for (int n = 0; n < 4; ++n)
          acc[m][n] = __builtin_amdgcn_mfma_f32_16x16x32_bf16(a[m], b[n][kk], acc[m][n], 0, 0, 0);
    }

    #pragma unroll
    for (int n = 0; n < 4; ++n) {
      int col = nBase + n * 16 + cc;
      if (col < NA) {
        #pragma unroll
        for (int m = 0; m < 4; ++m) {
          #pragma unroll
          for (int r = 0; r < 4; ++r) {
            int row = iBase + m * 16 + r0 + r;
            __builtin_nontemporal_store(acc[m][n][r], &out[(size_t)row * NA + col]);
          }
        }
      }
    }
  }
}

static inline char* alignup(char* p, size_t a) {
  return (char*)(((uintptr_t)p + a - 1) & ~(uintptr_t)(a - 1));
}

extern "C" void kernel_launch(void* const* d_in, const int* in_sizes, int n_in,
                              void* d_out, int out_size, void* d_ws, size_t ws_size,
                              hipStream_t stream) {
  const float* x      = (const float*)d_in[0];
  const float* mashup = (const float*)d_in[1];
  const float* domain = (const float*)d_in[2];
  const float* api    = (const float*)d_in[3];
  const float* Wsde   = (const float*)d_in[4];
  const float* bsde   = (const float*)d_in[5];
  const float* Wval   = (const float*)d_in[6];
  const float* bval   = (const float*)d_in[7];
  const float* Wkey   = (const float*)d_in[8];
  const float* bkey   = (const float*)d_in[9];
  const float* Wsie   = (const float*)d_in[10];
  const float* bsie   = (const float*)d_in[11];
  const int* esrc     = (const int*)d_in[12];
  const int* edst     = (const int*)d_in[13];
  float* out = (float*)d_out;

  // workspace layout (~90 MB)
  char* p = (char*)d_ws;
  u8*     M0y8  = (u8*)p; p += (size_t)NM * FEAT;                 // 6.4MB
  u8*     y0a8  = (u8*)p; p += (size_t)NA * FEAT;                 // 6.4MB
  u8*     y01a8 = (u8*)p; p += (size_t)NA * FEAT;                 // 6.4MB
  u8*     Sy8   = (u8*)p; p += (size_t)NM * FEAT;                 // 6.4MB
  bf16_t* outA  = (bf16_t*)p; p += (size_t)NA * FEAT * 2;         // 12.8MB
  bf16_t* Obf   = (bf16_t*)p; p += (size_t)NA * FEAT * 2;         // 12.8MB
  u16*    adjm  = (u16*)p;    p += (size_t)NM * MD * 2;           // 12.8MB
  u16*    adja  = (u16*)p;    p += (size_t)NA * MD * 2;           // 12.8MB
  float*  vmi   = (float*)p;  p += (size_t)BATCH * FEAT * 4;
  float*  vkey  = (float*)p;  p += (size_t)ND * FEAT * 4;
  float*  vval  = (float*)p;  p += (size_t)ND * FEAT * 4;
  bf16_t* zm    = (bf16_t*)p; p += (size_t)BATCH * FEAT * 2;
  int* cnt_m = (int*)p; p += (size_t)NM * 4;
  int* cnt_a = (int*)p; p += (size_t)NA * 4;
  float* dm  = (float*)p; p += (size_t)NM * 4;
  float* da  = (float*)p; p += (size_t)NA * 4;
  int* bcur  = (int*)p; p += 512 * 4;
  p = alignup(p, 16);
  bf16_t* wt0 = (bf16_t*)p; p += (size_t)FEAT * KDIM * 2;
  bf16_t* wt1 = (bf16_t*)p; p += (size_t)FEAT * KDIM * 2;
  bf16_t* wt2 = (bf16_t*)p; p += (size_t)FEAT * KDIM * 2;
  bf16_t* wt3 = (bf16_t*)p; p += (size_t)FEAT * KDIM * 2;
  // rec (2*NBIN*CAP*4B = 16.1MB) overlays M0y8+y0a8+y01a8 (19.2MB): dead
  // before proj_all/prop write those (fill_ell2 completes first, same stream).
  uint32_t* rec = (uint32_t*)M0y8;

  hipMemsetAsync(bcur, 0, 512 * sizeof(int), stream);

  // ---- graph build: two-level binning (157K global atomics vs 3.2M) ----
  fill_bin<<<F1B, 256, 0, stream>>>(esrc, edst, bcur, rec);
  fill_ell2<<<2 * NBIN, 256, 0, stream>>>(rec, bcur, adjm, adja, cnt_m, cnt_a);
  util_kernel<<<512 + (NM + 255) / 256, 256, 0, stream>>>(
      Wsde, Wkey, Wval, Wsie, wt0, wt1, wt2, wt3, cnt_m, cnt_a, dm, da);

  // ---- ALL projections in one dispatch (1596 blocks, gll + dbuf) ----
  proj_all<<<2 * PB64 + 32, 256, 0, stream>>>(
      mashup, api, x, domain, wt0, wt1, wt2, wt3,
      bsde, bkey, bval, bsie, M0y8, y0a8, vmi, vkey, vval, dm, da, outA);

  attn_kernel<<<BATCH, 256, 0, stream>>>(vmi, vkey, vval, zm);

  // ---- bipartite LightGCN (fp8 gathers): out_api = 0.25*(A0 + P^T(M0+M1+M2)) ----
  prop_p1<<<NA / 4, 256, 0, stream>>>((const uint32_t*)M0y8, (const uint32_t*)y0a8,
                                      (uint32_t*)y01a8, adja, cnt_a, da);
  prop_p2<<<NM / 4, 256, 0, stream>>>((const uint32_t*)y01a8, (const uint32_t*)M0y8,
                                      (uint32_t*)Sy8, adjm, cnt_m, dm);
  prop_p3<<<NA / 4, 256, 0, stream>>>((const uint32_t*)Sy8, outA, Obf,
                                      adja, cnt_a, da);

  pred_mfma<<<dim3((NA + 255) / 256, BATCH / 256), 256, 0, stream>>>(zm, Obf, out);
}

// Round 15
// 425.436 us; speedup vs baseline: 1.2555x; 1.0677x over previous
//
#include <hip/hip_runtime.h>
#include <hip/hip_bf16.h>
#include <cstddef>
#include <cstdint>

#define NM 50000
#define NA 50000
#define ND 500
#define FEAT 128
#define KDIM 768
#define BATCH 1024
#define NEDGE 1600000
#define MD 128            // ELL row capacity (deg ~ Poisson(32); P(>128) ~ 1e-38)

#define NBIN 196          // ceil(50000/256) node bins of 256 nodes
#define CAP 10240         // records per bin (expected 8163, 23 sigma headroom)
#define F1B 400           // fill_bin blocks
#define F1E (NEDGE / F1B) // 4000 edges per block (exact)

#define PB64 782          // ceil(50000/64) blocks per big projection (BM=64)
#define PKT  24           // K tiles (768/32)

typedef __bf16 bf16_t;
typedef bf16_t bf16x8 __attribute__((ext_vector_type(8)));
typedef bf16_t bf16x4 __attribute__((ext_vector_type(4)));
typedef float f32x4 __attribute__((ext_vector_type(4)));
typedef float f32x2 __attribute__((ext_vector_type(2)));
typedef unsigned short u16;
typedef unsigned char u8;

__device__ __forceinline__ float sigf(float x) { return 1.0f / (1.0f + __expf(-x)); }

// ---- fp8 e4m3 (OCP) helpers: HW v_cvt pack/unpack ----
__device__ __forceinline__ float4 dec4fp8(uint32_t w) {
  f32x2 lo = __builtin_amdgcn_cvt_pk_f32_fp8(w, false);
  f32x2 hi = __builtin_amdgcn_cvt_pk_f32_fp8(w, true);
  return make_float4(lo[0], lo[1], hi[0], hi[1]);
}
__device__ __forceinline__ u8 enc1fp8(float a) {
  return (u8)(__builtin_amdgcn_cvt_pk_fp8_f32(a, a, 0, false) & 0xff);
}

// ---- async global->LDS, 16B per lane (dest = wave-uniform base + lane*16) ----
__device__ __forceinline__ void gll16(const void* g, void* l) {
  __builtin_amdgcn_global_load_lds(
      (const __attribute__((address_space(1))) unsigned int*)g,
      (__attribute__((address_space(3))) unsigned int*)l, 16, 0, 0);
}

// ---------------- fill pass 1: edges -> bin-bucketed packed records -----------
__global__ __launch_bounds__(256) void fill_bin(
    const int* __restrict__ src, const int* __restrict__ dst,
    int* __restrict__ bcur, uint32_t* __restrict__ rec /* [2*NBIN][CAP] */)
{
  __shared__ uint32_t edg[F1E];      // 16 KB
  __shared__ int hist[2 * NBIN];
  __shared__ int base[2 * NBIN];
  const int tid = threadIdx.x;
  for (int i = tid; i < 2 * NBIN; i += 256) hist[i] = 0;
  __syncthreads();
  const int e0 = blockIdx.x * F1E;
  for (int i = tid; i < F1E; i += 256) {
    int s = __builtin_nontemporal_load(&src[e0 + i]);
    int d = __builtin_nontemporal_load(&dst[e0 + i]);
    edg[i] = ((uint32_t)s << 16) | (uint32_t)d;
    atomicAdd(&hist[s >> 8], 1);
    atomicAdd(&hist[NBIN + (d >> 8)], 1);
  }
  __syncthreads();
  for (int i = tid; i < 2 * NBIN; i += 256) {
    int c = hist[i];
    base[i] = c ? atomicAdd(&bcur[i], c) : 0;
    hist[i] = 0;  // reuse as emit cursor
  }
  __syncthreads();
  for (int i = tid; i < F1E; i += 256) {
    uint32_t e = edg[i];
    int s = (int)(e >> 16), d = (int)(e & 0xffffu);
    int bm = s >> 8, ba = NBIN + (d >> 8);
    int rm = base[bm] + atomicAdd(&hist[bm], 1);
    int ra = base[ba] + atomicAdd(&hist[ba], 1);
    if (rm < CAP) rec[(size_t)bm * CAP + rm] = e;
    if (ra < CAP) rec[(size_t)ba * CAP + ra] = ((uint32_t)d << 16) | (uint32_t)s;
  }
}

// ---------------- fill pass 2: records -> ELL rows + exact degrees ------------
__global__ __launch_bounds__(256) void fill_ell2(
    const uint32_t* __restrict__ rec, const int* __restrict__ bcur,
    u16* __restrict__ adjm, u16* __restrict__ adja,
    int* __restrict__ cnt_m, int* __restrict__ cnt_a)
{
  __shared__ int cnt256[256];
  const int g = blockIdx.x;                 // 0..2*NBIN-1
  const int side = g >= NBIN;
  const int bin = side ? g - NBIN : g;
  u16* adj = side ? adja : adjm;
  int* cnt = side ? cnt_a : cnt_m;
  cnt256[threadIdx.x] = 0;
  __syncthreads();
  int n = bcur[g]; if (n > CAP) n = CAP;
  const uint32_t* rb = rec + (size_t)g * CAP;
  for (int i = threadIdx.x; i < n; i += 256) {
    uint32_t r = rb[i];
    int node = (int)(r >> 16);
    int rk = atomicAdd(&cnt256[node & 255], 1);
    if (rk < MD) adj[(size_t)node * MD + rk] = (u16)(r & 0xffffu);
  }
  __syncthreads();
  int node = bin * 256 + threadIdx.x;
  if (node < NM) cnt[node] = cnt256[threadIdx.x];
}

// ---------------- util: 4x weight transpose->bf16 + deg->dinv ----------------
__global__ __launch_bounds__(256) void util_kernel(
    const float* __restrict__ W0, const float* __restrict__ W1,
    const float* __restrict__ W2, const float* __restrict__ W3,
    bf16_t* __restrict__ T0, bf16_t* __restrict__ T1,
    bf16_t* __restrict__ T2, bf16_t* __restrict__ T3,
    const int* __restrict__ cnt_m, const int* __restrict__ cnt_a,
    float* __restrict__ dm, float* __restrict__ da)
{
  const int b = blockIdx.x;
  if (b < 512) {
    const float* W = (b < 128) ? W0 : (b < 256) ? W1 : (b < 384) ? W2 : W3;
    bf16_t* T      = (b < 128) ? T0 : (b < 256) ? T1 : (b < 384) ? T2 : T3;
    int c = b & 127;
    for (int k = threadIdx.x; k < KDIM; k += 256)
      T[(size_t)c * KDIM + k] = (bf16_t)W[(size_t)k * FEAT + c];
  } else {
    int i = (b - 512) * 256 + threadIdx.x;
    if (i < NM) { int c = cnt_m[i]; dm[i] = c > 0 ? rsqrtf((float)c) : 0.f; }
    if (i < NA) { int c = cnt_a[i]; da[i] = c > 0 ? rsqrtf((float)c) : 0.f; }
  }
}

// ---------------- projection, BM=64, gll + 3-stage pipeline -------------------
// C = sigmoid(A[M,768] @ W + b). OM: 0 = fp32 out, 2 = fp8 out (row-scaled).
// LDS passed in from kernel (single allocation across template instantiations).
// Fragment-major LDS, conflict-free b128 reads. 3 tile-buffers of 16KB; iter t
// issues tile t+2's 4 gll loads then s_waitcnt vmcnt(8) (tile t landed; ~2
// iterations of latency cover). No vmcnt(0) drain inside the loop.
template<int OM>
__device__ __forceinline__ void proj_body(
    char* smraw,
    const float* __restrict__ A, const bf16_t* __restrict__ Wt,
    const float* __restrict__ bias, void* __restrict__ Cout, int M, int rowBase,
    const float* __restrict__ rowscale, bf16_t* __restrict__ C2)
{
  const int tid = threadIdx.x;
  const int lane = tid & 63;
  const int wid = tid >> 6;

  // staging sources (per-lane; 16B granules)
  int arow = rowBase + wid * 16 + (lane & 15); if (arow > M - 1) arow = M - 1;
  const float*  asrc  = A  + (size_t)arow * KDIM + ((lane >> 4) * 8);
  const bf16_t* bsrc0 = Wt + (size_t)((2 * wid) * 16 + (lane & 15)) * KDIM + ((lane >> 4) * 8);
  const bf16_t* bsrc1 = Wt + (size_t)((2 * wid + 1) * 16 + (lane & 15)) * KDIM + ((lane >> 4) * 8);

  f32x4 acc[2][4];
  #pragma unroll
  for (int m = 0; m < 2; ++m)
    #pragma unroll
    for (int n = 0; n < 4; ++n)
      acc[m][n] = (f32x4){0.f, 0.f, 0.f, 0.f};

  const int fA = (wid >> 1) * 2;        // this wave's A frags: fA, fA+1
  const int fB = (wid & 1) * 4;         // this wave's B frags: fB..fB+3

  // stage tile kt into buffer s (each wave: 4 gll16)
  auto stage = [&](int kt, int s) {
    const int k0 = kt * 32;
    char* base = smraw + s * 16384;
    gll16(asrc + k0,      base + wid * 2048);
    gll16(asrc + k0 + 4,  base + wid * 2048 + 1024);
    gll16(bsrc0 + k0,     base + 8192 + (2 * wid) * 1024);
    gll16(bsrc1 + k0,     base + 8192 + (2 * wid + 1) * 1024);
  };

  stage(0, 0);
  stage(1, 1);

  for (int kt = 0; kt < PKT; ++kt) {
    if (kt + 2 < PKT) {
      stage(kt + 2, (kt + 2) % 3);
      asm volatile("s_waitcnt vmcnt(8)" ::: "memory");
    } else if (kt + 1 < PKT) {
      asm volatile("s_waitcnt vmcnt(4)" ::: "memory");
    } else {
      asm volatile("s_waitcnt vmcnt(0)" ::: "memory");
    }
    __builtin_amdgcn_s_barrier();
    asm volatile("" ::: "memory");

    const char* bb = smraw + (kt % 3) * 16384;
    bf16x8 a[2], b[4];
    #pragma unroll
    for (int m = 0; m < 2; ++m) {
      f32x4 lo = *(const f32x4*)(bb + (fA + m) * 2048 + lane * 16);
      f32x4 hi = *(const f32x4*)(bb + (fA + m) * 2048 + 1024 + lane * 16);
      bf16x8 t;
      t[0] = (bf16_t)lo[0]; t[1] = (bf16_t)lo[1]; t[2] = (bf16_t)lo[2]; t[3] = (bf16_t)lo[3];
      t[4] = (bf16_t)hi[0]; t[5] = (bf16_t)hi[1]; t[6] = (bf16_t)hi[2]; t[7] = (bf16_t)hi[3];
      a[m] = t;
    }
    #pragma unroll
    for (int n = 0; n < 4; ++n)
      b[n] = *(const bf16x8*)(bb + 8192 + (fB + n) * 1024 + lane * 16);
    #pragma unroll
    for (int m = 0; m < 2; ++m)
      #pragma unroll
      for (int n = 0; n < 4; ++n)
        acc[m][n] = __builtin_amdgcn_mfma_f32_16x16x32_bf16(a[m], b[n], acc[m][n], 0, 0, 0);

    asm volatile("" ::: "memory");
    __builtin_amdgcn_s_barrier();
  }

  // C frag layout: col=lane&15, row=(lane>>4)*4+reg
  const int wRow = (wid >> 1) * 32, wCol = (wid & 1) * 64;
  const int r0 = (lane >> 4) * 4, cc = lane & 15;
  #pragma unroll
  for (int n = 0; n < 4; ++n) {
    int col = wCol + n * 16 + cc;
    float bb = bias[col];
    #pragma unroll
    for (int m = 0; m < 2; ++m) {
      #pragma unroll
      for (int r = 0; r < 4; ++r) {
        int row = rowBase + wRow + m * 16 + r0 + r;
        if (row < M) {
          float v = sigf(acc[m][n][r] + bb);
          float sc = rowscale ? rowscale[row] : 1.0f;
          if constexpr (OM == 2)
            ((u8*)Cout)[(size_t)row * FEAT + col] = enc1fp8(v * sc);
          else
            ((float*)Cout)[(size_t)row * FEAT + col] = v * sc;
          if (C2) C2[(size_t)row * FEAT + col] = (bf16_t)(0.25f * v);
        }
      }
    }
  }
}

// ---------------- ALL projections, one dispatch (1596 blocks, BM=64) ----------
// [0,782): mashup->M0y8(fp8,dm); [782,1564): api->y0a8(fp8,da)+outA;
// [1564,1580): x->vmi; [1580,1588): domain->vkey; [1588,1596): domain->vval.
__global__ __launch_bounds__(256) void proj_all(
    const float* __restrict__ mashup, const float* __restrict__ api,
    const float* __restrict__ x, const float* __restrict__ domain,
    const bf16_t* __restrict__ wt0, const bf16_t* __restrict__ wt1,
    const bf16_t* __restrict__ wt2, const bf16_t* __restrict__ wt3,
    const float* __restrict__ bsde, const float* __restrict__ bkey,
    const float* __restrict__ bval, const float* __restrict__ bsie,
    u8* __restrict__ M0y8, u8* __restrict__ y0a8,
    float* __restrict__ vmi, float* __restrict__ vkey, float* __restrict__ vval,
    const float* __restrict__ dm, const float* __restrict__ da,
    bf16_t* __restrict__ outA)
{
  __shared__ alignas(16) char smem[3 * 16384];   // shared across instantiations
  const int b = blockIdx.x;
  if (b < PB64)
    proj_body<2>(smem, mashup, wt0, bsde, M0y8, NM, b * 64, dm, nullptr);
  else if (b < 2 * PB64)
    proj_body<2>(smem, api, wt3, bsie, y0a8, NA, (b - PB64) * 64, da, outA);
  else if (b < 2 * PB64 + 16)
    proj_body<0>(smem, x, wt0, bsde, vmi, BATCH, (b - 2 * PB64) * 64, nullptr, nullptr);
  else if (b < 2 * PB64 + 24)
    proj_body<0>(smem, domain, wt1, bkey, vkey, ND, (b - 2 * PB64 - 16) * 64, nullptr, nullptr);
  else
    proj_body<0>(smem, domain, wt2, bval, vval, ND, (b - 2 * PB64 - 24) * 64, nullptr, nullptr);
}

// ---------------- attention (phase-B split across both thread halves) ---------
__global__ __launch_bounds__(256) void attn_kernel(
    const float* __restrict__ vmi, const float* __restrict__ vkey,
    const float* __restrict__ vval, bf16_t* __restrict__ zm)
{
  const int i = blockIdx.x;
  const int tid = threadIdx.x;
  __shared__ float vs[FEAT];
  __shared__ float al[ND];
  __shared__ float red[4];
  __shared__ float ps[256];
  __shared__ float totS;
  if (tid < FEAT) vs[tid] = vmi[(size_t)i * FEAT + tid];
  __syncthreads();
  float part = 0.f;
  for (int j = tid; j < ND; j += 256) {
    const float* kr = vkey + (size_t)j * FEAT;
    float dot = 0.f;
    #pragma unroll 8
    for (int k = 0; k < FEAT; k += 4) {
      float4 kv = *(const float4*)(kr + k);
      dot += vs[k] * kv.x + vs[k + 1] * kv.y + vs[k + 2] * kv.z + vs[k + 3] * kv.w;
    }
    al[j] = dot;
    part += dot;
  }
  #pragma unroll
  for (int o = 32; o > 0; o >>= 1) part += __shfl_down(part, o, 64);
  if ((tid & 63) == 0) red[tid >> 6] = part;
  __syncthreads();
  if (tid == 0) totS = red[0] + red[1] + red[2] + red[3];
  // phase B: thread = (half h, feature f); each half sums 250 of the 500 rows
  const int f = tid & 127, h = tid >> 7;
  float s = 0.f;
  const float* vv = vval + (size_t)h * 250 * FEAT + f;
  #pragma unroll 5
  for (int j = 0; j < 250; ++j) s += al[h * 250 + j] * vv[(size_t)j * FEAT];
  ps[tid] = s;
  __syncthreads();
  if (tid < FEAT) {
    float z = 0.5f * ((ps[tid] + ps[128 + tid]) / totS + vs[tid]);
    zm[(size_t)i * FEAT + tid] = (bf16_t)z;
  }
}

// ---------------- fp8 row-gather: half-wave per alternate neighbor ------------
__device__ __forceinline__ float4 gatherF8(const uint32_t* __restrict__ base32,
                                           const u16* __restrict__ row,
                                           int n, int half)
{
  float4 acc = make_float4(0.f, 0.f, 0.f, 0.f);
  int j = half;
  while (j + 14 < n) {
    int u[8];
    #pragma unroll
    for (int q = 0; q < 8; ++q) u[q] = row[j + 2 * q];
    uint32_t w[8];
    #pragma unroll
    for (int q = 0; q < 8; ++q) w[q] = base32[(size_t)u[q] * 32];
    #pragma unroll
    for (int q = 0; q < 8; ++q) {
      float4 v = dec4fp8(w[q]);
      acc.x += v.x; acc.y += v.y; acc.z += v.z; acc.w += v.w;
    }
    j += 16;
  }
  while (j < n) {
    float4 v = dec4fp8(base32[(size_t)row[j] * 32]);
    acc.x += v.x; acc.y += v.y; acc.z += v.z; acc.w += v.w;
    j += 2;
  }
  return acc;
}

#define REDUCE_HALVES(acc)                    \
  acc.x += __shfl_xor(acc.x, 32);             \
  acc.y += __shfl_xor(acc.y, 32);             \
  acc.z += __shfl_xor(acc.z, 32);             \
  acc.w += __shfl_xor(acc.w, 32);

// ---- pass1 (api side): y01a = y0a + da^2 * sum_{m in N(a)} M0y[m] ------------
__global__ __launch_bounds__(256) void prop_p1(
    const uint32_t* __restrict__ M0y8, const uint32_t* __restrict__ y0a8,
    uint32_t* __restrict__ y01a8,
    const u16* __restrict__ adja, const int* __restrict__ cnt_a,
    const float* __restrict__ da)
{
  const int a = blockIdx.x * 4 + (threadIdx.x >> 6);
  const int lane = threadIdx.x & 63;
  const int half = lane >> 5, sl = lane & 31;
  int n = cnt_a[a]; if (n > MD) n = MD;
  float4 acc = gatherF8(M0y8 + sl, adja + (size_t)a * MD, n, half);
  REDUCE_HALVES(acc)
  if (half == 0) {
    const float d = da[a];
    const float s2 = d * d;
    float4 b = dec4fp8(y0a8[(size_t)a * 32 + sl]);
    uint32_t o = __builtin_amdgcn_cvt_pk_fp8_f32(b.x + s2 * acc.x, b.y + s2 * acc.y, 0, false);
    o = __builtin_amdgcn_cvt_pk_fp8_f32(b.z + s2 * acc.z, b.w + s2 * acc.w, o, true);
    y01a8[(size_t)a * 32 + sl] = o;
  }
}

// ---- pass2 (mashup side): Sy = M0y + dm^2 * sum_{a in N(m)} y01a[a] ----------
__global__ __launch_bounds__(256) void prop_p2(
    const uint32_t* __restrict__ y01a8, const uint32_t* __restrict__ M0y8,
    uint32_t* __restrict__ Sy8,
    const u16* __restrict__ adjm, const int* __restrict__ cnt_m,
    const float* __restrict__ dm)
{
  const int m = blockIdx.x * 4 + (threadIdx.x >> 6);
  const int lane = threadIdx.x & 63;
  const int half = lane >> 5, sl = lane & 31;
  int n = cnt_m[m]; if (n > MD) n = MD;
  float4 acc = gatherF8(y01a8 + sl, adjm + (size_t)m * MD, n, half);
  REDUCE_HALVES(acc)
  if (half == 0) {
    const float d = dm[m];
    const float s2 = d * d;
    float4 b = dec4fp8(M0y8[(size_t)m * 32 + sl]);
    uint32_t o = __builtin_amdgcn_cvt_pk_fp8_f32(b.x + s2 * acc.x, b.y + s2 * acc.y, 0, false);
    o = __builtin_amdgcn_cvt_pk_fp8_f32(b.z + s2 * acc.z, b.w + s2 * acc.w, o, true);
    Sy8[(size_t)m * 32 + sl] = o;
  }
}

// ---- pass3 (api side): O = 0.25*A0 + 0.25*da * sum_{m in N(a)} Sy[m] ---------
__global__ __launch_bounds__(256) void prop_p3(
    const uint32_t* __restrict__ Sy8, const bf16_t* __restrict__ outA,
    bf16_t* __restrict__ Obf,
    const u16* __restrict__ adja, const int* __restrict__ cnt_a,
    const float* __restrict__ da)
{
  const int a = blockIdx.x * 4 + (threadIdx.x >> 6);
  const int lane = threadIdx.x & 63;
  const int half = lane >> 5, sl = lane & 31;
  int n = cnt_a[a]; if (n > MD) n = MD;
  float4 acc = gatherF8(Sy8 + sl, adja + (size_t)a * MD, n, half);
  REDUCE_HALVES(acc)
  if (half == 0) {
    const float q = 0.25f * da[a];
    bf16x4 pv = *(const bf16x4*)(outA + (size_t)a * FEAT + 4 * sl);
    bf16x4 o;
    o[0] = (bf16_t)((float)pv[0] + q * acc.x);
    o[1] = (bf16_t)((float)pv[1] + q * acc.y);
    o[2] = (bf16_t)((float)pv[2] + q * acc.z);
    o[3] = (bf16_t)((float)pv[3] + q * acc.w);
    *(bf16x4*)(Obf + (size_t)a * FEAT + 4 * sl) = o;
  }
}

// ---------------- pred = Z[1024,128] @ O[50000,128]^T, bf16 MFMA --------------
__global__ __launch_bounds__(256) void pred_mfma(
    const bf16_t* __restrict__ Z, const bf16_t* __restrict__ O,
    float* __restrict__ out)
{
  const int lane = threadIdx.x & 63;
  const int wid = threadIdx.x >> 6;
  const int nBase = blockIdx.x * 256 + wid * 64;
  const int cc = lane & 15;
  const int kOff = (lane >> 4) * 8;

  bf16x8 b[4][4];
  #pragma unroll
  for (int n = 0; n < 4; ++n) {
    int c = nBase + n * 16 + cc;
    if (c > NA - 1) c = NA - 1;
    #pragma unroll
    for (int kk = 0; kk < 4; ++kk)
      b[n][kk] = *(const bf16x8*)(O + (size_t)c * FEAT + kk * 32 + kOff);
  }

  const int r0 = (lane >> 4) * 4;
  #pragma unroll
  for (int it = 0; it < 4; ++it) {
    const int iBase = blockIdx.y * 256 + it * 64;
    f32x4 acc[4][4];
    #pragma unroll
    for (int m = 0; m < 4; ++m)
      #pragma unroll
      for (int n = 0; n < 4; ++n)
        acc[m][n] = (f32x4){0.f, 0.f, 0.f, 0.f};

    #pragma unroll
    for (int kk = 0; kk < 4; ++kk) {
      bf16x8 a[4];
      #pragma unroll
      for (int m = 0; m < 4; ++m)
        a[m] = *(const bf16x8*)(Z + (size_t)(iBase + cc + m * 16) * FEAT + kk * 32 + kOff);
      #pragma unroll
      for (int m = 0; m < 4; ++m)
        #pragma unroll
        for (int n = 0; n < 4; ++n)
          acc[m][n] = __builtin_amdgcn_mfma_f32_16x16x32_bf16(a[m], b[n][kk], acc[m][n], 0, 0, 0);
    }

    #pragma unroll
    for (int n = 0; n < 4; ++n) {
      int col = nBase + n * 16 + cc;
      if (col < NA) {
        #pragma unroll
        for (int m = 0; m < 4; ++m) {
          #pragma unroll
          for (int r = 0; r < 4; ++r) {
            int row = iBase + m * 16 + r0 + r;
            __builtin_nontemporal_store(acc[m][n][r], &out[(size_t)row * NA + col]);
          }
        }
      }
    }
  }
}

static inline char* alignup(char* p, size_t a) {
  return (char*)(((uintptr_t)p + a - 1) & ~(uintptr_t)(a - 1));
}

extern "C" void kernel_launch(void* const* d_in, const int* in_sizes, int n_in,
                              void* d_out, int out_size, void* d_ws, size_t ws_size,
                              hipStream_t stream) {
  const float* x      = (const float*)d_in[0];
  const float* mashup = (const float*)d_in[1];
  const float* domain = (const float*)d_in[2];
  const float* api    = (const float*)d_in[3];
  const float* Wsde   = (const float*)d_in[4];
  const float* bsde   = (const float*)d_in[5];
  const float* Wval   = (const float*)d_in[6];
  const float* bval   = (const float*)d_in[7];
  const float* Wkey   = (const float*)d_in[8];
  const float* bkey   = (const float*)d_in[9];
  const float* Wsie   = (const float*)d_in[10];
  const float* bsie   = (const float*)d_in[11];
  const int* esrc     = (const int*)d_in[12];
  const int* edst     = (const int*)d_in[13];
  float* out = (float*)d_out;

  // workspace layout (~90 MB)
  char* p = (char*)d_ws;
  u8*     M0y8  = (u8*)p; p += (size_t)NM * FEAT;                 // 6.4MB
  u8*     y0a8  = (u8*)p; p += (size_t)NA * FEAT;                 // 6.4MB
  u8*     y01a8 = (u8*)p; p += (size_t)NA * FEAT;                 // 6.4MB
  u8*     Sy8   = (u8*)p; p += (size_t)NM * FEAT;                 // 6.4MB
  bf16_t* outA  = (bf16_t*)p; p += (size_t)NA * FEAT * 2;         // 12.8MB
  bf16_t* Obf   = (bf16_t*)p; p += (size_t)NA * FEAT * 2;         // 12.8MB
  u16*    adjm  = (u16*)p;    p += (size_t)NM * MD * 2;           // 12.8MB
  u16*    adja  = (u16*)p;    p += (size_t)NA * MD * 2;           // 12.8MB
  float*  vmi   = (float*)p;  p += (size_t)BATCH * FEAT * 4;
  float*  vkey  = (float*)p;  p += (size_t)ND * FEAT * 4;
  float*  vval  = (float*)p;  p += (size_t)ND * FEAT * 4;
  bf16_t* zm    = (bf16_t*)p; p += (size_t)BATCH * FEAT * 2;
  int* cnt_m = (int*)p; p += (size_t)NM * 4;
  int* cnt_a = (int*)p; p += (size_t)NA * 4;
  float* dm  = (float*)p; p += (size_t)NM * 4;
  float* da  = (float*)p; p += (size_t)NA * 4;
  int* bcur  = (int*)p; p += 512 * 4;
  p = alignup(p, 16);
  bf16_t* wt0 = (bf16_t*)p; p += (size_t)FEAT * KDIM * 2;
  bf16_t* wt1 = (bf16_t*)p; p += (size_t)FEAT * KDIM * 2;
  bf16_t* wt2 = (bf16_t*)p; p += (size_t)FEAT * KDIM * 2;
  bf16_t* wt3 = (bf16_t*)p; p += (size_t)FEAT * KDIM * 2;
  // rec (2*NBIN*CAP*4B = 16.1MB) overlays M0y8+y0a8+y01a8 (19.2MB): dead
  // before proj_all/prop write those (fill_ell2 completes first, same stream).
  uint32_t* rec = (uint32_t*)M0y8;

  hipMemsetAsync(bcur, 0, 512 * sizeof(int), stream);

  // ---- graph build: two-level binning (157K global atomics vs 3.2M) ----
  fill_bin<<<F1B, 256, 0, stream>>>(esrc, edst, bcur, rec);
  fill_ell2<<<2 * NBIN, 256, 0, stream>>>(rec, bcur, adjm, adja, cnt_m, cnt_a);
  util_kernel<<<512 + (NM + 255) / 256, 256, 0, stream>>>(
      Wsde, Wkey, Wval, Wsie, wt0, wt1, wt2, wt3, cnt_m, cnt_a, dm, da);

  // ---- ALL projections in one dispatch (1596 blocks, gll + 3-stage) ----
  proj_all<<<2 * PB64 + 32, 256, 0, stream>>>(
      mashup, api, x, domain, wt0, wt1, wt2, wt3,
      bsde, bkey, bval, bsie, M0y8, y0a8, vmi, vkey, vval, dm, da, outA);

  attn_kernel<<<BATCH, 256, 0, stream>>>(vmi, vkey, vval, zm);

  // ---- bipartite LightGCN (fp8 gathers): out_api = 0.25*(A0 + P^T(M0+M1+M2)) ----
  prop_p1<<<NA / 4, 256, 0, stream>>>((const uint32_t*)M0y8, (const uint32_t*)y0a8,
                                      (uint32_t*)y01a8, adja, cnt_a, da);
  prop_p2<<<NM / 4, 256, 0, stream>>>((const uint32_t*)y01a8, (const uint32_t*)M0y8,
                                      (uint32_t*)Sy8, adjm, cnt_m, dm);
  prop_p3<<<NA / 4, 256, 0, stream>>>((const uint32_t*)Sy8, outA, Obf,
                                      adja, cnt_a, da);

  pred_mfma<<<dim3((NA + 255) / 256, BATCH / 256), 256, 0, stream>>>(zm, Obf, out);
}

// Round 16
// 402.353 us; speedup vs baseline: 1.3276x; 1.0574x over previous
//
#include <hip/hip_runtime.h>
#include <hip/hip_bf16.h>
#include <cstddef>
#include <cstdint>

#define NM 50000
#define NA 50000
#define ND 500
#define FEAT 128
#define KDIM 768
#define BATCH 1024
#define NEDGE 1600000
#define MD 128            // ELL row capacity (deg ~ Poisson(32); P(>128) ~ 1e-38)

#define NBIN 196          // ceil(50000/256) node bins of 256 nodes
#define CAP 10240         // records per bin (expected 8163, 23 sigma headroom)
#define F1B 400           // fill_bin blocks (edge part)
#define F1E (NEDGE / F1B) // 4000 edges per block (exact)

#define PB128 391         // ceil(50000/128) blocks per big projection (8 waves x 16 rows)
#define PKT   24          // K tiles (768/32)

typedef __bf16 bf16_t;
typedef bf16_t bf16x8 __attribute__((ext_vector_type(8)));
typedef bf16_t bf16x4 __attribute__((ext_vector_type(4)));
typedef float f32x4 __attribute__((ext_vector_type(4)));
typedef float f32x2 __attribute__((ext_vector_type(2)));
typedef unsigned short u16;
typedef unsigned char u8;

__device__ __forceinline__ float sigf(float x) { return 1.0f / (1.0f + __expf(-x)); }

// ---- fp8 e4m3 (OCP) helpers: HW v_cvt pack/unpack ----
__device__ __forceinline__ float4 dec4fp8(uint32_t w) {
  f32x2 lo = __builtin_amdgcn_cvt_pk_f32_fp8(w, false);
  f32x2 hi = __builtin_amdgcn_cvt_pk_f32_fp8(w, true);
  return make_float4(lo[0], lo[1], hi[0], hi[1]);
}
__device__ __forceinline__ u8 enc1fp8(float a) {
  return (u8)(__builtin_amdgcn_cvt_pk_fp8_f32(a, a, 0, false) & 0xff);
}

// ---- async global->LDS, 16B per lane (dest = wave-uniform base + lane*16) ----
__device__ __forceinline__ void gll16(const void* g, void* l) {
  __builtin_amdgcn_global_load_lds(
      (const __attribute__((address_space(1))) unsigned int*)g,
      (__attribute__((address_space(3))) unsigned int*)l, 16, 0, 0);
}

// ---------------- fill pass 1 + weight transpose, one dispatch ----------------
// blocks [0,400): edges -> bin-bucketed packed records (LDS histogram, ONE
// global atomic per (block,bin)); blocks [400,912): W[768,128]->Wt[128,768] bf16.
__global__ __launch_bounds__(256) void fill_bin_wt(
    const int* __restrict__ src, const int* __restrict__ dst,
    int* __restrict__ bcur, uint32_t* __restrict__ rec,
    const float* __restrict__ W0, const float* __restrict__ W1,
    const float* __restrict__ W2, const float* __restrict__ W3,
    bf16_t* __restrict__ T0, bf16_t* __restrict__ T1,
    bf16_t* __restrict__ T2, bf16_t* __restrict__ T3)
{
  __shared__ uint32_t edg[F1E];      // 16 KB
  __shared__ int hist[2 * NBIN];
  __shared__ int base[2 * NBIN];
  if (blockIdx.x >= F1B) {
    const int b = blockIdx.x - F1B;      // 0..511
    const float* W = (b < 128) ? W0 : (b < 256) ? W1 : (b < 384) ? W2 : W3;
    bf16_t* T      = (b < 128) ? T0 : (b < 256) ? T1 : (b < 384) ? T2 : T3;
    int c = b & 127;
    for (int k = threadIdx.x; k < KDIM; k += 256)
      T[(size_t)c * KDIM + k] = (bf16_t)W[(size_t)k * FEAT + c];
    return;
  }
  const int tid = threadIdx.x;
  for (int i = tid; i < 2 * NBIN; i += 256) hist[i] = 0;
  __syncthreads();
  const int e0 = blockIdx.x * F1E;
  for (int i = tid; i < F1E; i += 256) {
    int s = __builtin_nontemporal_load(&src[e0 + i]);
    int d = __builtin_nontemporal_load(&dst[e0 + i]);
    edg[i] = ((uint32_t)s << 16) | (uint32_t)d;
    atomicAdd(&hist[s >> 8], 1);
    atomicAdd(&hist[NBIN + (d >> 8)], 1);
  }
  __syncthreads();
  for (int i = tid; i < 2 * NBIN; i += 256) {
    int c = hist[i];
    base[i] = c ? atomicAdd(&bcur[i], c) : 0;
    hist[i] = 0;  // reuse as emit cursor
  }
  __syncthreads();
  for (int i = tid; i < F1E; i += 256) {
    uint32_t e = edg[i];
    int s = (int)(e >> 16), d = (int)(e & 0xffffu);
    int bm = s >> 8, ba = NBIN + (d >> 8);
    int rm = base[bm] + atomicAdd(&hist[bm], 1);
    int ra = base[ba] + atomicAdd(&hist[ba], 1);
    if (rm < CAP) rec[(size_t)bm * CAP + rm] = e;
    if (ra < CAP) rec[(size_t)ba * CAP + ra] = ((uint32_t)d << 16) | (uint32_t)s;
  }
}

// ---------------- fill pass 2: records -> ELL rows + degrees + dinv -----------
__global__ __launch_bounds__(256) void fill_ell2(
    const uint32_t* __restrict__ rec, const int* __restrict__ bcur,
    u16* __restrict__ adjm, u16* __restrict__ adja,
    int* __restrict__ cnt_m, int* __restrict__ cnt_a,
    float* __restrict__ dm, float* __restrict__ da)
{
  __shared__ int cnt256[256];
  const int g = blockIdx.x;                 // 0..2*NBIN-1
  const int side = g >= NBIN;
  const int bin = side ? g - NBIN : g;
  u16* adj = side ? adja : adjm;
  int* cnt = side ? cnt_a : cnt_m;
  float* dv = side ? da : dm;
  cnt256[threadIdx.x] = 0;
  __syncthreads();
  int n = bcur[g]; if (n > CAP) n = CAP;
  const uint32_t* rb = rec + (size_t)g * CAP;
  for (int i = threadIdx.x; i < n; i += 256) {
    uint32_t r = rb[i];
    int node = (int)(r >> 16);
    int rk = atomicAdd(&cnt256[node & 255], 1);
    if (rk < MD) adj[(size_t)node * MD + rk] = (u16)(r & 0xffffu);
  }
  __syncthreads();
  int node = bin * 256 + threadIdx.x;
  if (node < NM) {
    int c = cnt256[threadIdx.x];
    cnt[node] = c;
    dv[node] = c > 0 ? rsqrtf((float)c) : 0.f;
  }
}

// ---------------- projection, BM=128, 8 waves, gll + 2-stage ------------------
// C = sigmoid(A[M,768] @ W + b). OM: 0 = fp32 out, 2 = fp8 out (row-scaled).
// Wave w owns rows [w*16,w*16+16) x all 128 cols; stages its own A-frag (2 gll)
// + B-frag w (1 gll) per K-tile. 2-stage double buffer, counted vmcnt(3) +
// raw s_barrier (each wave certifies its own quarter; barrier joins).
template<int OM>
__device__ __forceinline__ void proj8(
    char* smraw,
    const float* __restrict__ A, const bf16_t* __restrict__ Wt,
    const float* __restrict__ bias, void* __restrict__ Cout, int M, int rowBase,
    const float* __restrict__ rowscale, bf16_t* __restrict__ C2)
{
  const int tid = threadIdx.x;
  const int lane = tid & 63;
  const int wid = tid >> 6;                 // 0..7

  int arow = rowBase + wid * 16 + (lane & 15); if (arow > M - 1) arow = M - 1;
  const float*  asrc = A  + (size_t)arow * KDIM + ((lane >> 4) * 8);
  const bf16_t* bsrc = Wt + (size_t)(wid * 16 + (lane & 15)) * KDIM + ((lane >> 4) * 8);

  f32x4 acc[8];
  #pragma unroll
  for (int n = 0; n < 8; ++n) acc[n] = (f32x4){0.f, 0.f, 0.f, 0.f};

  // per-stage layout (24KB): [A: 8 frags x 2KB][B: 8 frags x 1KB]
  auto stage = [&](int kt, int s) {
    const int k0 = kt * 32;
    char* base = smraw + s * 24576;
    gll16(asrc + k0,     base + wid * 2048);
    gll16(asrc + k0 + 4, base + wid * 2048 + 1024);
    gll16(bsrc + k0,     base + 16384 + wid * 1024);
  };

  stage(0, 0);

  for (int kt = 0; kt < PKT; ++kt) {
    if (kt + 1 < PKT) {
      stage(kt + 1, (kt + 1) & 1);
      asm volatile("s_waitcnt vmcnt(3)" ::: "memory");   // stage kt landed
    } else {
      asm volatile("s_waitcnt vmcnt(0)" ::: "memory");
    }
    __builtin_amdgcn_s_barrier();
    asm volatile("" ::: "memory");

    const char* bb = smraw + (kt & 1) * 24576;
    f32x4 lo = *(const f32x4*)(bb + wid * 2048 + lane * 16);
    f32x4 hi = *(const f32x4*)(bb + wid * 2048 + 1024 + lane * 16);
    bf16x8 a;
    a[0] = (bf16_t)lo[0]; a[1] = (bf16_t)lo[1]; a[2] = (bf16_t)lo[2]; a[3] = (bf16_t)lo[3];
    a[4] = (bf16_t)hi[0]; a[5] = (bf16_t)hi[1]; a[6] = (bf16_t)hi[2]; a[7] = (bf16_t)hi[3];
    #pragma unroll
    for (int n = 0; n < 8; ++n) {
      bf16x8 bfr = *(const bf16x8*)(bb + 16384 + n * 1024 + lane * 16);
      acc[n] = __builtin_amdgcn_mfma_f32_16x16x32_bf16(a, bfr, acc[n], 0, 0, 0);
    }

    asm volatile("" ::: "memory");
    __builtin_amdgcn_s_barrier();
  }

  // C frag layout: col=lane&15, row=(lane>>4)*4+reg
  const int r0 = (lane >> 4) * 4, cc = lane & 15;
  #pragma unroll
  for (int n = 0; n < 8; ++n) {
    int col = n * 16 + cc;
    float bb = bias[col];
    #pragma unroll
    for (int r = 0; r < 4; ++r) {
      int row = rowBase + wid * 16 + r0 + r;
      if (row < M) {
        float v = sigf(acc[n][r] + bb);
        float sc = rowscale ? rowscale[row] : 1.0f;
        if constexpr (OM == 2)
          ((u8*)Cout)[(size_t)row * FEAT + col] = enc1fp8(v * sc);
        else
          ((float*)Cout)[(size_t)row * FEAT + col] = v * sc;
        if (C2) C2[(size_t)row * FEAT + col] = (bf16_t)(0.25f * v);
      }
    }
  }
}

// ---------------- ALL projections, one dispatch (798 blocks x 512 thr) --------
// [0,391): mashup->M0y8(fp8,dm); [391,782): api->y0a8(fp8,da)+outA;
// [782,790): x->vmi; [790,794): domain->vkey; [794,798): domain->vval.
__global__ __launch_bounds__(512, 4) void proj_all(
    const float* __restrict__ mashup, const float* __restrict__ api,
    const float* __restrict__ x, const float* __restrict__ domain,
    const bf16_t* __restrict__ wt0, const bf16_t* __restrict__ wt1,
    const bf16_t* __restrict__ wt2, const bf16_t* __restrict__ wt3,
    const float* __restrict__ bsde, const float* __restrict__ bkey,
    const float* __restrict__ bval, const float* __restrict__ bsie,
    u8* __restrict__ M0y8, u8* __restrict__ y0a8,
    float* __restrict__ vmi, float* __restrict__ vkey, float* __restrict__ vval,
    const float* __restrict__ dm, const float* __restrict__ da,
    bf16_t* __restrict__ outA)
{
  __shared__ alignas(16) char smem[2 * 24576];   // 48KB, shared across branches
  const int b = blockIdx.x;
  if (b < PB128)
    proj8<2>(smem, mashup, wt0, bsde, M0y8, NM, b * 128, dm, nullptr);
  else if (b < 2 * PB128)
    proj8<2>(smem, api, wt3, bsie, y0a8, NA, (b - PB128) * 128, da, outA);
  else if (b < 2 * PB128 + 8)
    proj8<0>(smem, x, wt0, bsde, vmi, BATCH, (b - 2 * PB128) * 128, nullptr, nullptr);
  else if (b < 2 * PB128 + 12)
    proj8<0>(smem, domain, wt1, bkey, vkey, ND, (b - 2 * PB128 - 8) * 128, nullptr, nullptr);
  else
    proj8<0>(smem, domain, wt2, bval, vval, ND, (b - 2 * PB128 - 12) * 128, nullptr, nullptr);
}

// ---------------- attention (phase-B split across both thread halves) ---------
__global__ __launch_bounds__(256) void attn_kernel(
    const float* __restrict__ vmi, const float* __restrict__ vkey,
    const float* __restrict__ vval, bf16_t* __restrict__ zm)
{
  const int i = blockIdx.x;
  const int tid = threadIdx.x;
  __shared__ float vs[FEAT];
  __shared__ float al[ND];
  __shared__ float red[4];
  __shared__ float ps[256];
  __shared__ float totS;
  if (tid < FEAT) vs[tid] = vmi[(size_t)i * FEAT + tid];
  __syncthreads();
  float part = 0.f;
  for (int j = tid; j < ND; j += 256) {
    const float* kr = vkey + (size_t)j * FEAT;
    float dot = 0.f;
    #pragma unroll 8
    for (int k = 0; k < FEAT; k += 4) {
      float4 kv = *(const float4*)(kr + k);
      dot += vs[k] * kv.x + vs[k + 1] * kv.y + vs[k + 2] * kv.z + vs[k + 3] * kv.w;
    }
    al[j] = dot;
    part += dot;
  }
  #pragma unroll
  for (int o = 32; o > 0; o >>= 1) part += __shfl_down(part, o, 64);
  if ((tid & 63) == 0) red[tid >> 6] = part;
  __syncthreads();
  if (tid == 0) totS = red[0] + red[1] + red[2] + red[3];
  // phase B: thread = (half h, feature f); each half sums 250 of the 500 rows
  const int f = tid & 127, h = tid >> 7;
  float s = 0.f;
  const float* vv = vval + (size_t)h * 250 * FEAT + f;
  #pragma unroll 5
  for (int j = 0; j < 250; ++j) s += al[h * 250 + j] * vv[(size_t)j * FEAT];
  ps[tid] = s;
  __syncthreads();
  if (tid < FEAT) {
    float z = 0.5f * ((ps[tid] + ps[128 + tid]) / totS + vs[tid]);
    zm[(size_t)i * FEAT + tid] = (bf16_t)z;
  }
}

// ---------------- fp8 row-gather: half-wave per alternate neighbor ------------
__device__ __forceinline__ float4 gatherF8(const uint32_t* __restrict__ base32,
                                           const u16* __restrict__ row,
                                           int n, int half)
{
  float4 acc = make_float4(0.f, 0.f, 0.f, 0.f);
  int j = half;
  while (j + 14 < n) {
    int u[8];
    #pragma unroll
    for (int q = 0; q < 8; ++q) u[q] = row[j + 2 * q];
    uint32_t w[8];
    #pragma unroll
    for (int q = 0; q < 8; ++q) w[q] = base32[(size_t)u[q] * 32];
    #pragma unroll
    for (int q = 0; q < 8; ++q) {
      float4 v = dec4fp8(w[q]);
      acc.x += v.x; acc.y += v.y; acc.z += v.z; acc.w += v.w;
    }
    j += 16;
  }
  while (j < n) {
    float4 v = dec4fp8(base32[(size_t)row[j] * 32]);
    acc.x += v.x; acc.y += v.y; acc.z += v.z; acc.w += v.w;
    j += 2;
  }
  return acc;
}

#define REDUCE_HALVES(acc)                    \
  acc.x += __shfl_xor(acc.x, 32);             \
  acc.y += __shfl_xor(acc.y, 32);             \
  acc.z += __shfl_xor(acc.z, 32);             \
  acc.w += __shfl_xor(acc.w, 32);

// ---- pass1 (api side): y01a = y0a + da^2 * sum_{m in N(a)} M0y[m] ------------
__global__ __launch_bounds__(256) void prop_p1(
    const uint32_t* __restrict__ M0y8, const uint32_t* __restrict__ y0a8,
    uint32_t* __restrict__ y01a8,
    const u16* __restrict__ adja, const int* __restrict__ cnt_a,
    const float* __restrict__ da)
{
  const int a = blockIdx.x * 4 + (threadIdx.x >> 6);
  const int lane = threadIdx.x & 63;
  const int half = lane >> 5, sl = lane & 31;
  int n = cnt_a[a]; if (n > MD) n = MD;
  float4 acc = gatherF8(M0y8 + sl, adja + (size_t)a * MD, n, half);
  REDUCE_HALVES(acc)
  if (half == 0) {
    const float d = da[a];
    const float s2 = d * d;
    float4 b = dec4fp8(y0a8[(size_t)a * 32 + sl]);
    uint32_t o = __builtin_amdgcn_cvt_pk_fp8_f32(b.x + s2 * acc.x, b.y + s2 * acc.y, 0, false);
    o = __builtin_amdgcn_cvt_pk_fp8_f32(b.z + s2 * acc.z, b.w + s2 * acc.w, o, true);
    y01a8[(size_t)a * 32 + sl] = o;
  }
}

// ---- pass2 (mashup side): Sy = M0y + dm^2 * sum_{a in N(m)} y01a[a] ----------
__global__ __launch_bounds__(256) void prop_p2(
    const uint32_t* __restrict__ y01a8, const uint32_t* __restrict__ M0y8,
    uint32_t* __restrict__ Sy8,
    const u16* __restrict__ adjm, const int* __restrict__ cnt_m,
    const float* __restrict__ dm)
{
  const int m = blockIdx.x * 4 + (threadIdx.x >> 6);
  const int lane = threadIdx.x & 63;
  const int half = lane >> 5, sl = lane & 31;
  int n = cnt_m[m]; if (n > MD) n = MD;
  float4 acc = gatherF8(y01a8 + sl, adjm + (size_t)m * MD, n, half);
  REDUCE_HALVES(acc)
  if (half == 0) {
    const float d = dm[m];
    const float s2 = d * d;
    float4 b = dec4fp8(M0y8[(size_t)m * 32 + sl]);
    uint32_t o = __builtin_amdgcn_cvt_pk_fp8_f32(b.x + s2 * acc.x, b.y + s2 * acc.y, 0, false);
    o = __builtin_amdgcn_cvt_pk_fp8_f32(b.z + s2 * acc.z, b.w + s2 * acc.w, o, true);
    Sy8[(size_t)m * 32 + sl] = o;
  }
}

// ---- pass3 (api side): O = 0.25*A0 + 0.25*da * sum_{m in N(a)} Sy[m] ---------
__global__ __launch_bounds__(256) void prop_p3(
    const uint32_t* __restrict__ Sy8, const bf16_t* __restrict__ outA,
    bf16_t* __restrict__ Obf,
    const u16* __restrict__ adja, const int* __restrict__ cnt_a,
    const float* __restrict__ da)
{
  const int a = blockIdx.x * 4 + (threadIdx.x >> 6);
  const int lane = threadIdx.x & 63;
  const int half = lane >> 5, sl = lane & 31;
  int n = cnt_a[a]; if (n > MD) n = MD;
  float4 acc = gatherF8(Sy8 + sl, adja + (size_t)a * MD, n, half);
  REDUCE_HALVES(acc)
  if (half == 0) {
    const float q = 0.25f * da[a];
    bf16x4 pv = *(const bf16x4*)(outA + (size_t)a * FEAT + 4 * sl);
    bf16x4 o;
    o[0] = (bf16_t)((float)pv[0] + q * acc.x);
    o[1] = (bf16_t)((float)pv[1] + q * acc.y);
    o[2] = (bf16_t)((float)pv[2] + q * acc.z);
    o[3] = (bf16_t)((float)pv[3] + q * acc.w);
    *(bf16x4*)(Obf + (size_t)a * FEAT + 4 * sl) = o;
  }
}

// ---------------- pred = Z[1024,128] @ O[50000,128]^T, bf16 MFMA --------------
__global__ __launch_bounds__(256) void pred_mfma(
    const bf16_t* __restrict__ Z, const bf16_t* __restrict__ O,
    float* __restrict__ out)
{
  const int lane = threadIdx.x & 63;
  const int wid = threadIdx.x >> 6;
  const int nBase = blockIdx.x * 256 + wid * 64;
  const int cc = lane & 15;
  const int kOff = (lane >> 4) * 8;

  bf16x8 b[4][4];
  #pragma unroll
  for (int n = 0; n < 4; ++n) {
    int c = nBase + n * 16 + cc;
    if (c > NA - 1) c = NA - 1;
    #pragma unroll
    for (int kk = 0; kk < 4; ++kk)
      b[n][kk] = *(const bf16x8*)(O + (size_t)c * FEAT + kk * 32 + kOff);
  }

  const int r0 = (lane >> 4) * 4;
  #pragma unroll
  for (int it = 0; it < 4; ++it) {
    const int iBase = blockIdx.y * 256 + it * 64;
    f32x4 acc[4][4];
    #pragma unroll
    for (int m = 0; m < 4; ++m)
      #pragma unroll
      for (int n = 0; n < 4; ++n)
        acc[m][n] = (f32x4){0.f, 0.f, 0.f, 0.f};

    #pragma unroll
    for (int kk = 0; kk < 4; ++kk) {
      bf16x8 a[4];
      #pragma unroll
      for (int m = 0; m < 4; ++m)
        a[m] = *(const bf16x8*)(Z + (size_t)(iBase + cc + m * 16) * FEAT + kk * 32 + kOff);
      #pragma unroll
      for (int m = 0; m < 4; ++m)
        #pragma unroll
        for (int n = 0; n < 4; ++n)
          acc[m][n] = __builtin_amdgcn_mfma_f32_16x16x32_bf16(a[m], b[n][kk], acc[m][n], 0, 0, 0);
    }

    #pragma unroll
    for (int n = 0; n < 4; ++n) {
      int col = nBase + n * 16 + cc;
      if (col < NA) {
        #pragma unroll
        for (int m = 0; m < 4; ++m) {
          #pragma unroll
          for (int r = 0; r < 4; ++r) {
            int row = iBase + m * 16 + r0 + r;
            __builtin_nontemporal_store(acc[m][n][r], &out[(size_t)row * NA + col]);
          }
        }
      }
    }
  }
}

static inline char* alignup(char* p, size_t a) {
  return (char*)(((uintptr_t)p + a - 1) & ~(uintptr_t)(a - 1));
}

extern "C" void kernel_launch(void* const* d_in, const int* in_sizes, int n_in,
                              void* d_out, int out_size, void* d_ws, size_t ws_size,
                              hipStream_t stream) {
  const float* x      = (const float*)d_in[0];
  const float* mashup = (const float*)d_in[1];
  const float* domain = (const float*)d_in[2];
  const float* api    = (const float*)d_in[3];
  const float* Wsde   = (const float*)d_in[4];
  const float* bsde   = (const float*)d_in[5];
  const float* Wval   = (const float*)d_in[6];
  const float* bval   = (const float*)d_in[7];
  const float* Wkey   = (const float*)d_in[8];
  const float* bkey   = (const float*)d_in[9];
  const float* Wsie   = (const float*)d_in[10];
  const float* bsie   = (const float*)d_in[11];
  const int* esrc     = (const int*)d_in[12];
  const int* edst     = (const int*)d_in[13];
  float* out = (float*)d_out;

  // workspace layout (~90 MB)
  char* p = (char*)d_ws;
  u8*     M0y8  = (u8*)p; p += (size_t)NM * FEAT;                 // 6.4MB
  u8*     y0a8  = (u8*)p; p += (size_t)NA * FEAT;                 // 6.4MB
  u8*     y01a8 = (u8*)p; p += (size_t)NA * FEAT;                 // 6.4MB
  u8*     Sy8   = (u8*)p; p += (size_t)NM * FEAT;                 // 6.4MB
  bf16_t* outA  = (bf16_t*)p; p += (size_t)NA * FEAT * 2;         // 12.8MB
  bf16_t* Obf   = (bf16_t*)p; p += (size_t)NA * FEAT * 2;         // 12.8MB
  u16*    adjm  = (u16*)p;    p += (size_t)NM * MD * 2;           // 12.8MB
  u16*    adja  = (u16*)p;    p += (size_t)NA * MD * 2;           // 12.8MB
  float*  vmi   = (float*)p;  p += (size_t)BATCH * FEAT * 4;
  float*  vkey  = (float*)p;  p += (size_t)ND * FEAT * 4;
  float*  vval  = (float*)p;  p += (size_t)ND * FEAT * 4;
  bf16_t* zm    = (bf16_t*)p; p += (size_t)BATCH * FEAT * 2;
  int* cnt_m = (int*)p; p += (size_t)NM * 4;
  int* cnt_a = (int*)p; p += (size_t)NA * 4;
  float* dm  = (float*)p; p += (size_t)NM * 4;
  float* da  = (float*)p; p += (size_t)NA * 4;
  int* bcur  = (int*)p; p += 512 * 4;
  p = alignup(p, 16);
  bf16_t* wt0 = (bf16_t*)p; p += (size_t)FEAT * KDIM * 2;
  bf16_t* wt1 = (bf16_t*)p; p += (size_t)FEAT * KDIM * 2;
  bf16_t* wt2 = (bf16_t*)p; p += (size_t)FEAT * KDIM * 2;
  bf16_t* wt3 = (bf16_t*)p; p += (size_t)FEAT * KDIM * 2;
  // rec (2*NBIN*CAP*4B = 16.1MB) overlays M0y8+y0a8+y01a8 (19.2MB): dead
  // before proj_all/prop write those (fill_ell2 completes first, same stream).
  uint32_t* rec = (uint32_t*)M0y8;

  hipMemsetAsync(bcur, 0, 512 * sizeof(int), stream);

  // ---- graph build (+ weight transpose fused into the same dispatch) ----
  fill_bin_wt<<<F1B + 512, 256, 0, stream>>>(esrc, edst, bcur, rec,
                                             Wsde, Wkey, Wval, Wsie,
                                             wt0, wt1, wt2, wt3);
  fill_ell2<<<2 * NBIN, 256, 0, stream>>>(rec, bcur, adjm, adja,
                                          cnt_m, cnt_a, dm, da);

  // ---- ALL projections in one dispatch (798 blocks x 512 threads) ----
  proj_all<<<2 * PB128 + 16, 512, 0, stream>>>(
      mashup, api, x, domain, wt0, wt1, wt2, wt3,
      bsde, bkey, bval, bsie, M0y8, y0a8, vmi, vkey, vval, dm, da, outA);

  attn_kernel<<<BATCH, 256, 0, stream>>>(vmi, vkey, vval, zm);

  // ---- bipartite LightGCN (fp8 gathers): out_api = 0.25*(A0 + P^T(M0+M1+M2)) ----
  prop_p1<<<NA / 4, 256, 0, stream>>>((const uint32_t*)M0y8, (const uint32_t*)y0a8,
                                      (uint32_t*)y01a8, adja, cnt_a, da);
  prop_p2<<<NM / 4, 256, 0, stream>>>((const uint32_t*)y01a8, (const uint32_t*)M0y8,
                                      (uint32_t*)Sy8, adjm, cnt_m, dm);
  prop_p3<<<NA / 4, 256, 0, stream>>>((const uint32_t*)Sy8, outA, Obf,
                                      adja, cnt_a, da);

  pred_mfma<<<dim3((NA + 255) / 256, BATCH / 256), 256, 0, stream>>>(zm, Obf, out);
}